// Round 12
// baseline (508.461 us; speedup 1.0000x reference)
//
#include <hip/hip_runtime.h>
#include <hip/hip_bf16.h>

// ---------------------------------------------------------------------------
// GINE x2 + mean-pool + FC.
// CSR build: hist/scan + XCC-ID-sliced scatter: each block reads its REAL XCD
// id (s_getreg HW_REG_XCC_ID, m09-verified) and drains a per-slice chunk
// queue; slice k's csr region (3.2MB) is then written only from XCD k's L2 ->
// partial 16B stores merge into full-line writebacks.  Steal-fallback keeps
// correctness independent of block->XCD mapping (G16).
// agg1 (thread/node, 7ch) -> p1; mlp_mfma<8> -> h1 bf16;
// agg2 (wave/node quarter-parallel gathers) -> p2 bf16; mlp_mfma<64> -> h2;
// pool_fc (block/graph, binary search on sorted batch).
// ---------------------------------------------------------------------------

#define CHUNK 1024
#define SCHUNK 2048  // edges per scatter work-queue chunk

typedef __attribute__((ext_vector_type(8))) short bf16x8;
typedef __attribute__((ext_vector_type(4))) float f32x4;
typedef __attribute__((ext_vector_type(4))) unsigned int u32x4;

__device__ __forceinline__ float bf2f(unsigned short u) {
  return __uint_as_float(((unsigned)u) << 16);
}
__device__ __forceinline__ unsigned short f2bf(float f) {
  __hip_bfloat16 hb = __float2bfloat16(f);
  return *reinterpret_cast<unsigned short*>(&hb);
}
__device__ __forceinline__ int get_xcc_id() {
  int x;
  asm volatile("s_getreg_b32 %0, hwreg(HW_REG_XCC_ID)" : "=s"(x));
  return x & 7;
}

__global__ __launch_bounds__(256) void hist_kernel(
    const int* __restrict__ dstIdx, int* __restrict__ deg, int E) {
  int i = blockIdx.x * 256 + threadIdx.x;
  int e0 = i * 4;
  if (e0 + 3 < E) {
    int4 d = reinterpret_cast<const int4*>(dstIdx)[i];
    atomicAdd(&deg[d.x], 1);
    atomicAdd(&deg[d.y], 1);
    atomicAdd(&deg[d.z], 1);
    atomicAdd(&deg[d.w], 1);
  } else {
    for (int e = e0; e < E; ++e) atomicAdd(&deg[dstIdx[e]], 1);
  }
}

__global__ __launch_bounds__(256) void scan1_kernel(
    const int* __restrict__ deg, int* __restrict__ cursor,
    int* __restrict__ blockSum, int N) {
  __shared__ int sd[256];
  int t = threadIdx.x;
  int base = blockIdx.x * CHUNK + t * 4;
  int v0 = (base + 0 < N) ? deg[base + 0] : 0;
  int v1 = (base + 1 < N) ? deg[base + 1] : 0;
  int v2 = (base + 2 < N) ? deg[base + 2] : 0;
  int v3 = (base + 3 < N) ? deg[base + 3] : 0;
  int ts = v0 + v1 + v2 + v3;
  sd[t] = ts;
  __syncthreads();
  for (int off = 1; off < 256; off <<= 1) {
    int xv = (t >= off) ? sd[t - off] : 0;
    __syncthreads();
    sd[t] += xv;
    __syncthreads();
  }
  int excl = sd[t] - ts;
  if (t == 255) blockSum[blockIdx.x] = sd[255];
  if (base + 0 < N) cursor[base + 0] = excl;
  if (base + 1 < N) cursor[base + 1] = excl + v0;
  if (base + 2 < N) cursor[base + 2] = excl + v0 + v1;
  if (base + 3 < N) cursor[base + 3] = excl + v0 + v1 + v2;
}

__global__ __launch_bounds__(256) void scan2_kernel(
    const int* __restrict__ blockSum, int* __restrict__ blockOff, int nb) {
  __shared__ int sd[256];
  int t = threadIdx.x;
  int base = t * 4;
  int v0 = (base + 0 < nb) ? blockSum[base + 0] : 0;
  int v1 = (base + 1 < nb) ? blockSum[base + 1] : 0;
  int v2 = (base + 2 < nb) ? blockSum[base + 2] : 0;
  int v3 = (base + 3 < nb) ? blockSum[base + 3] : 0;
  int ts = v0 + v1 + v2 + v3;
  sd[t] = ts;
  __syncthreads();
  for (int off = 1; off < 256; off <<= 1) {
    int xv = (t >= off) ? sd[t - off] : 0;
    __syncthreads();
    sd[t] += xv;
    __syncthreads();
  }
  int excl = sd[t] - ts;
  if (base + 0 < nb) blockOff[base + 0] = excl;
  if (base + 1 < nb) blockOff[base + 1] = excl + v0;
  if (base + 2 < nb) blockOff[base + 2] = excl + v0 + v1;
  if (base + 3 < nb) blockOff[base + 3] = excl + v0 + v1 + v2;
}

__global__ __launch_bounds__(256) void scan3_kernel(
    int* __restrict__ cursor, const int* __restrict__ blockOff, int N) {
  int i = blockIdx.x * 256 + threadIdx.x;
  if (i < N) cursor[i] += blockOff[i >> 10];  // log2(CHUNK)
}

// XCC-sliced scatter.  Slice k owns dst in [k*N/8,(k+1)*N/8).  Blocks drain
// the chunk queue of THEIR OWN XCD's slice first (write locality), then steal
// from the others (correctness regardless of XCD mapping).
__global__ __launch_bounds__(256) void scatter_kernel(
    const int* __restrict__ srcIdx, const int* __restrict__ dstIdx,
    const float* __restrict__ ea, int* __restrict__ cursor,
    int* __restrict__ chunkCtr, u32x4* __restrict__ csr, int E, int N) {
  __shared__ int sChunk;
  int myx = get_xcc_id();
  int nchunks = (E + SCHUNK - 1) / SCHUNK;
  for (int t = 0; t < 8; ++t) {
    int slice = (myx + t) & 7;
    int lo = (int)(((long long)slice * N) >> 3);
    int hi = (int)(((long long)(slice + 1) * N) >> 3);
    while (true) {
      if (threadIdx.x == 0) sChunk = atomicAdd(&chunkCtr[slice], 1);
      __syncthreads();
      int chunk = sChunk;
      __syncthreads();
      if (chunk >= nchunks) break;
      int e0 = chunk * SCHUNK;
      int e1 = min(e0 + SCHUNK, E);
      for (int e = e0 + threadIdx.x; e < e1; e += 256) {
        int d = dstIdx[e];  // cached: read by all 8 cohorts (L2/L3)
        if (d >= lo && d < hi) {
          int s = __builtin_nontemporal_load(&srcIdx[e]);
          f32x4 a = __builtin_nontemporal_load(
              reinterpret_cast<const f32x4*>(ea) + e);
          u32x4 v;
          v[0] = (unsigned)s;
          v[1] = (unsigned)f2bf(a[0]) | ((unsigned)f2bf(a[1]) << 16);
          v[2] = (unsigned)f2bf(a[2]) | ((unsigned)f2bf(a[3]) << 16);
          v[3] = 0;
          int pos = atomicAdd(&cursor[d], 1);
          csr[pos] = v;  // merges in this XCD's L2
        }
      }
    }
  }
}

// agg1: thread per node; 7-channel gather-accumulate; writes p1 = x + agg
// (f32, stride 8, slot 7 = 0).
__global__ __launch_bounds__(256) void agg1_kernel(
    const float* __restrict__ x, const u32x4* __restrict__ csr,
    const float* __restrict__ We1, const float* __restrict__ be1,
    const int* __restrict__ deg, const int* __restrict__ cursor,
    float* __restrict__ p1, int N) {
  int n = blockIdx.x * 256 + threadIdx.x;
  if (n >= N) return;
  float w[28], b[7];
#pragma unroll
  for (int i = 0; i < 28; ++i) w[i] = We1[i];
#pragma unroll
  for (int i = 0; i < 7; ++i) b[i] = be1[i];
  int end = cursor[n];
  int start = end - deg[n];
  float acc[7];
#pragma unroll
  for (int c = 0; c < 7; ++c) acc[c] = 0.f;
  for (int i = start; i < end; ++i) {
    u32x4 u = csr[i];
    int s = (int)u[0];
    float a0 = __uint_as_float(u[1] << 16);
    float a1 = __uint_as_float(u[1] & 0xffff0000u);
    float a2 = __uint_as_float(u[2] << 16);
    float a3 = __uint_as_float(u[2] & 0xffff0000u);
    const float* xs = x + (size_t)s * 7;
#pragma unroll
    for (int c = 0; c < 7; ++c) {
      float v = b[c] + a0 * w[c] + a1 * w[7 + c] + a2 * w[14 + c] +
                a3 * w[21 + c] + xs[c];
      acc[c] += fmaxf(v, 0.f);
    }
  }
  const float* xn = x + (size_t)n * 7;
#pragma unroll
  for (int c = 0; c < 7; ++c) p1[(size_t)n * 8 + c] = acc[c] + xn[c];
  p1[(size_t)n * 8 + 7] = 0.f;
}

// agg2: wave per node, quarter-parallel (lane = edge-slot q, channel-quad m).
// No MLP, no LDS -> low VGPR, high occupancy.  Writes p2 bf16[N][64].
__global__ __launch_bounds__(256) void agg2_kernel(
    const unsigned short* __restrict__ h1b, const u32x4* __restrict__ csr,
    const int* __restrict__ deg, const int* __restrict__ cursor,
    const float* __restrict__ We2, const float* __restrict__ be2,
    unsigned short* __restrict__ p2b, int N) {
  int w = threadIdx.x >> 6, j = threadIdx.x & 63;
  int q = j >> 4;  // edge slot 0..3
  int m = j & 15;  // channel quad
  float4 ew0 = *reinterpret_cast<const float4*>(&We2[0 * 64 + m * 4]);
  float4 ew1 = *reinterpret_cast<const float4*>(&We2[1 * 64 + m * 4]);
  float4 ew2 = *reinterpret_cast<const float4*>(&We2[2 * 64 + m * 4]);
  float4 ew3 = *reinterpret_cast<const float4*>(&We2[3 * 64 + m * 4]);
  float4 eb = *reinterpret_cast<const float4*>(&be2[m * 4]);
  int wid = blockIdx.x * 4 + w;
  int nw = gridDim.x * 4;
  for (int n = wid; n < N; n += nw) {
    int end = cursor[n];
    int start = end - deg[n];
    float acc0 = 0.f, acc1 = 0.f, acc2 = 0.f, acc3 = 0.f;
    for (int base = start; base < end; base += 64) {
      int cnt = min(64, end - base);
      int sl = 0;
      int ax = 0, ay = 0;
      if (base + j < end) {
        u32x4 u = csr[base + j];  // coalesced 16B, cached
        sl = (int)u[0];
        ax = (int)u[1];
        ay = (int)u[2];
      }
      int ngrp = (cnt + 3) >> 2;
      for (int it = 0; it < ngrp; ++it) {  // wave-uniform trip count
        int lane = it * 4 + q;
        int s = __shfl(sl, lane);
        unsigned uax = (unsigned)__shfl(ax, lane);
        unsigned uay = (unsigned)__shfl(ay, lane);
        ushort4 hv =
            *reinterpret_cast<const ushort4*>(&h1b[(size_t)s * 64 + m * 4]);
        float a0 = __uint_as_float(uax << 16);
        float a1 = __uint_as_float(uax & 0xffff0000u);
        float a2 = __uint_as_float(uay << 16);
        float a3 = __uint_as_float(uay & 0xffff0000u);
        float e0 = eb.x + a0 * ew0.x + a1 * ew1.x + a2 * ew2.x + a3 * ew3.x;
        float e1 = eb.y + a0 * ew0.y + a1 * ew1.y + a2 * ew2.y + a3 * ew3.y;
        float e2 = eb.z + a0 * ew0.z + a1 * ew1.z + a2 * ew2.z + a3 * ew3.z;
        float e3 = eb.w + a0 * ew0.w + a1 * ew1.w + a2 * ew2.w + a3 * ew3.w;
        if (lane < cnt) {
          acc0 += fmaxf(bf2f(hv.x) + e0, 0.f);
          acc1 += fmaxf(bf2f(hv.y) + e1, 0.f);
          acc2 += fmaxf(bf2f(hv.z) + e2, 0.f);
          acc3 += fmaxf(bf2f(hv.w) + e3, 0.f);
        }
      }
    }
    acc0 += __shfl_xor(acc0, 16); acc0 += __shfl_xor(acc0, 32);
    acc1 += __shfl_xor(acc1, 16); acc1 += __shfl_xor(acc1, 32);
    acc2 += __shfl_xor(acc2, 16); acc2 += __shfl_xor(acc2, 32);
    acc3 += __shfl_xor(acc3, 16); acc3 += __shfl_xor(acc3, 32);
    ushort4 sv =
        *reinterpret_cast<const ushort4*>(&h1b[(size_t)n * 64 + m * 4]);
    if (q == 0) {  // one quarter writes the (reduced) row
      ushort4 o;
      o.x = f2bf(acc0 + bf2f(sv.x));
      o.y = f2bf(acc1 + bf2f(sv.y));
      o.z = f2bf(acc2 + bf2f(sv.z));
      o.w = f2bf(acc3 + bf2f(sv.w));
      *reinterpret_cast<ushort4*>(&p2b[(size_t)n * 64 + m * 4]) = o;
    }
  }
}

// Fused 2-layer MLP via MFMA 16x16x32 bf16.  KIN=8: input f32[N][8]
// (rows 7..31 of Wa zero-padded); KIN=64: input bf16[N][64].
// Layouts (m89-verified): A row=lane&15, k=(lane>>4)*8+i; B col=lane&15,
// k=(lane>>4)*8+i; C/D col=lane&15, row=(lane>>4)*4+reg.
template <int KIN>
__global__ __launch_bounds__(256) void mlp_mfma_kernel(
    const void* __restrict__ pin, const float* __restrict__ Wa,
    const float* __restrict__ ba, const float* __restrict__ Wb,
    const float* __restrict__ bb, unsigned short* __restrict__ hout, int N) {
  __shared__ unsigned short t_lds[4][16 * 72];  // row stride 144B (9x16B)
  int w = threadIdx.x >> 6, l = threadIdx.x & 63;
  int lr = l & 15, lq = l >> 4;
  constexpr int KSA = (KIN == 8) ? 1 : 2;
  constexpr int VROWS = (KIN == 8) ? 7 : 64;
  bf16x8 wa[2][4], wb[2][4];
#pragma unroll
  for (int ks = 0; ks < KSA; ++ks)
#pragma unroll
    for (int c = 0; c < 4; ++c) {
      bf16x8 f;
#pragma unroll
      for (int r = 0; r < 8; ++r) {
        int row = ks * 32 + lq * 8 + r;
        float v = (row < VROWS) ? Wa[row * 64 + c * 16 + lr] : 0.f;
        f[r] = (short)f2bf(v);
      }
      wa[ks][c] = f;
    }
#pragma unroll
  for (int ks = 0; ks < 2; ++ks)
#pragma unroll
    for (int c = 0; c < 4; ++c) {
      bf16x8 f;
#pragma unroll
      for (int r = 0; r < 8; ++r)
        f[r] = (short)f2bf(Wb[(ks * 32 + lq * 8 + r) * 64 + c * 16 + lr]);
      wb[ks][c] = f;
    }
  float vba[4], vbb[4];
#pragma unroll
  for (int c = 0; c < 4; ++c) {
    vba[c] = ba[c * 16 + lr];
    vbb[c] = bb[c * 16 + lr];
  }
  unsigned short* tl = t_lds[w];
  int ntiles = (N + 15) >> 4;
  for (int tile = blockIdx.x * 4 + w; tile < ntiles; tile += gridDim.x * 4) {
    int n0 = tile << 4;
    int arow = n0 + lr;
    bf16x8 af0, af1;
#pragma unroll
    for (int r = 0; r < 8; ++r) { af0[r] = 0; af1[r] = 0; }
    if (KIN == 8) {
      if (lq == 0 && arow < N) {
        const float* pr = (const float*)pin + (size_t)arow * 8;
#pragma unroll
        for (int r = 0; r < 8; ++r) af0[r] = (short)f2bf(pr[r]);
      }
    } else {
      if (arow < N) {
        const unsigned short* pr =
            (const unsigned short*)pin + (size_t)arow * 64 + lq * 8;
        af0 = *(const bf16x8*)(pr);
        af1 = *(const bf16x8*)(pr + 32);
      }
    }
    f32x4 accA[4];
#pragma unroll
    for (int c = 0; c < 4; ++c) {
      f32x4 a = {0.f, 0.f, 0.f, 0.f};
      a = __builtin_amdgcn_mfma_f32_16x16x32_bf16(af0, wa[0][c], a, 0, 0, 0);
      if (KSA == 2)
        a = __builtin_amdgcn_mfma_f32_16x16x32_bf16(af1, wa[1][c], a, 0, 0, 0);
      accA[c] = a;
    }
#pragma unroll
    for (int c = 0; c < 4; ++c)
#pragma unroll
      for (int r = 0; r < 4; ++r) {
        float v = fmaxf(accA[c][r] + vba[c], 0.f);
        tl[(lq * 4 + r) * 72 + c * 16 + lr] = f2bf(v);
      }
    bf16x8 tf0 = *(const bf16x8*)&tl[lr * 72 + lq * 8];
    bf16x8 tf1 = *(const bf16x8*)&tl[lr * 72 + 32 + lq * 8];
#pragma unroll
    for (int c = 0; c < 4; ++c) {
      f32x4 a = {0.f, 0.f, 0.f, 0.f};
      a = __builtin_amdgcn_mfma_f32_16x16x32_bf16(tf0, wb[0][c], a, 0, 0, 0);
      a = __builtin_amdgcn_mfma_f32_16x16x32_bf16(tf1, wb[1][c], a, 0, 0, 0);
#pragma unroll
      for (int r = 0; r < 4; ++r) {
        int row = n0 + lq * 4 + r;
        if (row < N) {
          float v = fmaxf(a[r] + vbb[c], 0.f);
          hout[(size_t)row * 64 + c * 16 + lr] = f2bf(v);
        }
      }
    }
  }
}

__global__ __launch_bounds__(64) void pool_fc_kernel(
    const unsigned short* __restrict__ h2b, const int* __restrict__ batch,
    const float* __restrict__ Wfc, const float* __restrict__ bfc,
    float* __restrict__ out, int N, int G) {
  int g = blockIdx.x;
  int j = threadIdx.x;  // 0..63
  int q = j >> 4;
  int m = j & 15;
  int lo = 0, hi = N;
  while (lo < hi) {
    int mid = (lo + hi) >> 1;
    if (batch[mid] < g) lo = mid + 1; else hi = mid;
  }
  int start = lo;
  lo = start; hi = N;
  while (lo < hi) {
    int mid = (lo + hi) >> 1;
    if (batch[mid] < g + 1) lo = mid + 1; else hi = mid;
  }
  int end = lo;
  int cnt = end - start;
  float s0 = 0.f, s1 = 0.f, s2 = 0.f, s3 = 0.f;
  int ngrp = (cnt + 3) >> 2;
  for (int it = 0; it < ngrp; ++it) {
    int r = start + it * 4 + q;
    if (r < end) {
      ushort4 hv =
          *reinterpret_cast<const ushort4*>(&h2b[(size_t)r * 64 + m * 4]);
      s0 += bf2f(hv.x);
      s1 += bf2f(hv.y);
      s2 += bf2f(hv.z);
      s3 += bf2f(hv.w);
    }
  }
  s0 += __shfl_xor(s0, 16); s0 += __shfl_xor(s0, 32);
  s1 += __shfl_xor(s1, 16); s1 += __shfl_xor(s1, 32);
  s2 += __shfl_xor(s2, 16); s2 += __shfl_xor(s2, 32);
  s3 += __shfl_xor(s3, 16); s3 += __shfl_xor(s3, 32);
  float inv = 1.f / fmaxf((float)cnt, 1.f);
  __shared__ float spool[64];
  if (q == 0) {
    spool[m * 4 + 0] = s0 * inv;
    spool[m * 4 + 1] = s1 * inv;
    spool[m * 4 + 2] = s2 * inv;
    spool[m * 4 + 3] = s3 * inv;
  }
  __syncthreads();
  if (j < 12) {
    float o = bfc[j];
#pragma unroll
    for (int k = 0; k < 64; ++k) o += spool[k] * Wfc[k * 12 + j];
    out[(size_t)g * 12 + j] = o;
  }
}

extern "C" void kernel_launch(void* const* d_in, const int* in_sizes, int n_in,
                              void* d_out, int out_size, void* d_ws,
                              size_t ws_size, hipStream_t stream) {
  const float* x   = (const float*)d_in[0];
  const float* ea  = (const float*)d_in[1];
  const float* We1 = (const float*)d_in[2];
  const float* be1 = (const float*)d_in[3];
  const float* We2 = (const float*)d_in[4];
  const float* be2 = (const float*)d_in[5];
  const float* W1a = (const float*)d_in[6];
  const float* b1a = (const float*)d_in[7];
  const float* W1b = (const float*)d_in[8];
  const float* b1b = (const float*)d_in[9];
  const float* W2a = (const float*)d_in[10];
  const float* b2a = (const float*)d_in[11];
  const float* W2b = (const float*)d_in[12];
  const float* b2b = (const float*)d_in[13];
  const float* Wfc = (const float*)d_in[14];
  const float* bfc = (const float*)d_in[15];
  const int* eidx  = (const int*)d_in[16];
  const int* batch = (const int*)d_in[17];

  int N = in_sizes[0] / 7;
  int E = in_sizes[1] / 4;
  int G = out_size / 12;
  const int* srcIdx = eidx;
  const int* dstIdx = eidx + E;

  char* ws = (char*)d_ws;
  int*   deg      = (int*)ws;             ws += (size_t)N * 4;
  int*   cursor   = (int*)ws;             ws += (size_t)N * 4;
  int*   blockSum = (int*)ws;             ws += 4096;
  int*   blockOff = (int*)ws;             ws += 4096;
  int*   chunkCtr = (int*)ws;             ws += 256;
  u32x4* csr      = (u32x4*)ws;           ws += (size_t)E * 16;
  float* p1       = (float*)ws;           ws += (size_t)N * 8 * 4;
  unsigned short* h1b = (unsigned short*)ws; ws += (size_t)N * 64 * 2;
  unsigned short* p2b = (unsigned short*)ws; ws += (size_t)N * 64 * 2;
  unsigned short* h2b = (unsigned short*)ws; /* += N*64*2 */
  // total ~ 0.8 + 25.6 + 3.2 + 3*12.8 ~= 68 MB

  int nb = (N + CHUNK - 1) / CHUNK;
  int ntiles = (N + 15) / 16;
  int mlpBlocks = (ntiles + 3) / 4;
  if (mlpBlocks > 1024) mlpBlocks = 1024;  // grid-stride

  hipMemsetAsync(deg, 0, (size_t)N * 4, stream);
  hipMemsetAsync(chunkCtr, 0, 256, stream);
  hist_kernel<<<((E + 3) / 4 + 255) / 256, 256, 0, stream>>>(dstIdx, deg, E);
  scan1_kernel<<<nb, 256, 0, stream>>>(deg, cursor, blockSum, N);
  scan2_kernel<<<1, 256, 0, stream>>>(blockSum, blockOff, nb);
  scan3_kernel<<<(N + 255) / 256, 256, 0, stream>>>(cursor, blockOff, N);
  scatter_kernel<<<2048, 256, 0, stream>>>(srcIdx, dstIdx, ea, cursor,
                                           chunkCtr, csr, E, N);
  agg1_kernel<<<(N + 255) / 256, 256, 0, stream>>>(x, csr, We1, be1, deg,
                                                   cursor, p1, N);
  mlp_mfma_kernel<8><<<mlpBlocks, 256, 0, stream>>>(p1, W1a, b1a, W1b, b1b,
                                                    h1b, N);
  agg2_kernel<<<2048, 256, 0, stream>>>(h1b, csr, deg, cursor, We2, be2, p2b,
                                        N);
  mlp_mfma_kernel<64><<<mlpBlocks, 256, 0, stream>>>(p2b, W2a, b2a, W2b, b2b,
                                                     h2b, N);
  pool_fc_kernel<<<G, 64, 0, stream>>>(h2b, batch, Wfc, bfc, (float*)d_out, N,
                                       G);
}

// Round 13
// 286.130 us; speedup vs baseline: 1.7770x; 1.7770x over previous
//
#include <hip/hip_runtime.h>
#include <hip/hip_bf16.h>

// ---------------------------------------------------------------------------
// GINE x2 + mean-pool + FC.
// CSR build WITHOUT scattered stores:
//   hist/scan -> cursor (pristine row starts)
//   passA: 2048-edge tiles, LDS counting-sort into 512 dst-buckets, flush
//          per-bucket runs (same-thread consecutive 16B stores -> line merge)
//   passB: block=bucket (~50KB), LDS scatter by per-node cursor, coalesced
//          csr write.  Records = {src, ea01.bf16x2, ea23.bf16x2, dst}.
// agg1 (thread/node) -> p1; mlp_mfma<8> -> h1 bf16;
// agg2 (wave/node quarter-parallel) -> p2 bf16; mlp_mfma<64> -> h2; pool_fc.
// ---------------------------------------------------------------------------

#define CHUNK 1024
#define NBUCK 512
#define TILE_A 2048
#define PB_CAP 3584  // passB LDS record capacity (mean 3125 + 8 sigma)

typedef __attribute__((ext_vector_type(8))) short bf16x8;
typedef __attribute__((ext_vector_type(4))) float f32x4;
typedef __attribute__((ext_vector_type(4))) unsigned int u32x4;

__device__ __forceinline__ float bf2f(unsigned short u) {
  return __uint_as_float(((unsigned)u) << 16);
}
__device__ __forceinline__ unsigned short f2bf(float f) {
  __hip_bfloat16 hb = __float2bfloat16(f);
  return *reinterpret_cast<unsigned short*>(&hb);
}
__device__ __forceinline__ int bucket_lo(int b, int N) {
  return (int)(((long long)b * N + (NBUCK - 1)) >> 9);  // ceil(b*N/512)
}

__global__ __launch_bounds__(256) void hist_kernel(
    const int* __restrict__ dstIdx, int* __restrict__ deg, int E) {
  int i = blockIdx.x * 256 + threadIdx.x;
  int e0 = i * 4;
  if (e0 + 3 < E) {
    int4 d = reinterpret_cast<const int4*>(dstIdx)[i];
    atomicAdd(&deg[d.x], 1);
    atomicAdd(&deg[d.y], 1);
    atomicAdd(&deg[d.z], 1);
    atomicAdd(&deg[d.w], 1);
  } else {
    for (int e = e0; e < E; ++e) atomicAdd(&deg[dstIdx[e]], 1);
  }
}

__global__ __launch_bounds__(256) void scan1_kernel(
    const int* __restrict__ deg, int* __restrict__ cursor,
    int* __restrict__ blockSum, int N) {
  __shared__ int sd[256];
  int t = threadIdx.x;
  int base = blockIdx.x * CHUNK + t * 4;
  int v0 = (base + 0 < N) ? deg[base + 0] : 0;
  int v1 = (base + 1 < N) ? deg[base + 1] : 0;
  int v2 = (base + 2 < N) ? deg[base + 2] : 0;
  int v3 = (base + 3 < N) ? deg[base + 3] : 0;
  int ts = v0 + v1 + v2 + v3;
  sd[t] = ts;
  __syncthreads();
  for (int off = 1; off < 256; off <<= 1) {
    int xv = (t >= off) ? sd[t - off] : 0;
    __syncthreads();
    sd[t] += xv;
    __syncthreads();
  }
  int excl = sd[t] - ts;
  if (t == 255) blockSum[blockIdx.x] = sd[255];
  if (base + 0 < N) cursor[base + 0] = excl;
  if (base + 1 < N) cursor[base + 1] = excl + v0;
  if (base + 2 < N) cursor[base + 2] = excl + v0 + v1;
  if (base + 3 < N) cursor[base + 3] = excl + v0 + v1 + v2;
}

__global__ __launch_bounds__(256) void scan2_kernel(
    const int* __restrict__ blockSum, int* __restrict__ blockOff, int nb) {
  __shared__ int sd[256];
  int t = threadIdx.x;
  int base = t * 4;
  int v0 = (base + 0 < nb) ? blockSum[base + 0] : 0;
  int v1 = (base + 1 < nb) ? blockSum[base + 1] : 0;
  int v2 = (base + 2 < nb) ? blockSum[base + 2] : 0;
  int v3 = (base + 3 < nb) ? blockSum[base + 3] : 0;
  int ts = v0 + v1 + v2 + v3;
  sd[t] = ts;
  __syncthreads();
  for (int off = 1; off < 256; off <<= 1) {
    int xv = (t >= off) ? sd[t - off] : 0;
    __syncthreads();
    sd[t] += xv;
    __syncthreads();
  }
  int excl = sd[t] - ts;
  if (base + 0 < nb) blockOff[base + 0] = excl;
  if (base + 1 < nb) blockOff[base + 1] = excl + v0;
  if (base + 2 < nb) blockOff[base + 2] = excl + v0 + v1;
  if (base + 3 < nb) blockOff[base + 3] = excl + v0 + v1 + v2;
}

__global__ __launch_bounds__(256) void scan3_kernel(
    int* __restrict__ cursor, const int* __restrict__ blockOff, int N) {
  int i = blockIdx.x * 256 + threadIdx.x;
  if (i < N) cursor[i] += blockOff[i >> 10];  // log2(CHUNK)
}

// bcur[b] = region start; cursor2 = pristine copy for overflow fallback.
__global__ __launch_bounds__(256) void initb_kernel(
    const int* __restrict__ cursor, int* __restrict__ bcur, int N) {
  int b = blockIdx.x * 256 + threadIdx.x;
  if (b < NBUCK) bcur[b] = cursor[bucket_lo(b, N)];
}
__global__ __launch_bounds__(256) void copycur_kernel(
    const int* __restrict__ cursor, int* __restrict__ cursor2, int N) {
  int i = blockIdx.x * 256 + threadIdx.x;
  if (i < N) cursor2[i] = cursor[i];
}

// passA: per-tile LDS counting sort into 512 buckets; flush contiguous runs.
__global__ __launch_bounds__(256) void binA_kernel(
    const int* __restrict__ srcIdx, const int* __restrict__ dstIdx,
    const float* __restrict__ ea, int* __restrict__ bcur,
    u32x4* __restrict__ binned, int E, double invN) {
  __shared__ u32x4 recs[TILE_A];  // 32 KB
  __shared__ int cnt[NBUCK];      // 2 KB (becomes inclusive scan)
  __shared__ int off[NBUCK];      // 2 KB (exclusive offsets)
  int t = threadIdx.x;
  int e0 = blockIdx.x * TILE_A;
  int valid = min(TILE_A, E - e0);

  cnt[t] = 0;
  cnt[t + 256] = 0;
  __syncthreads();

  u32x4 rec[8];
  int bkt[8], slot[8];
#pragma unroll
  for (int k = 0; k < 8; ++k) {
    int idx = t + k * 256;
    bkt[k] = -1;
    if (idx < valid) {
      int e = e0 + idx;
      int d = dstIdx[e];
      int s = __builtin_nontemporal_load(&srcIdx[e]);
      f32x4 a = __builtin_nontemporal_load(
          reinterpret_cast<const f32x4*>(ea) + e);
      u32x4 v;
      v[0] = (unsigned)s;
      v[1] = (unsigned)f2bf(a[0]) | ((unsigned)f2bf(a[1]) << 16);
      v[2] = (unsigned)f2bf(a[2]) | ((unsigned)f2bf(a[3]) << 16);
      v[3] = (unsigned)d;
      rec[k] = v;
      int b = (int)((double)((long long)d << 9) * invN);  // exact floor (see r12)
      bkt[k] = b;
      slot[k] = atomicAdd(&cnt[b], 1);
    }
  }
  __syncthreads();
  int c0 = cnt[t], c1 = cnt[t + 256];
  // inclusive Hillis-Steele over 512
  for (int o = 1; o < NBUCK; o <<= 1) {
    int v0 = (t >= o) ? cnt[t - o] : 0;
    int v1 = (t + 256 >= o) ? cnt[t + 256 - o] : 0;
    __syncthreads();
    cnt[t] += v0;
    cnt[t + 256] += v1;
    __syncthreads();
  }
  off[t] = cnt[t] - c0;
  off[t + 256] = cnt[t + 256] - c1;
  __syncthreads();
#pragma unroll
  for (int k = 0; k < 8; ++k)
    if (bkt[k] >= 0) recs[off[bkt[k]] + slot[k]] = rec[k];
  __syncthreads();
  // flush: thread t owns buckets t and t+256; same-thread consecutive 16B
  // stores cover whole lines -> merged writeback.
#pragma unroll
  for (int h = 0; h < 2; ++h) {
    int b = t + h * 256;
    int c = (h == 0) ? c0 : c1;
    if (c > 0) {
      int g = atomicAdd(&bcur[b], c);
      int o = off[b];
      for (int k = 0; k < c; ++k) binned[g + k] = recs[o + k];
    }
  }
}

// passB: block = bucket; sort records by dst via LDS scatter; coalesced write.
__global__ __launch_bounds__(256) void binB_kernel(
    const u32x4* __restrict__ binned, const int* __restrict__ cursor,
    int* __restrict__ cursor2, u32x4* __restrict__ csr, int E, int N) {
  __shared__ u32x4 lrec[PB_CAP];  // 56 KB
  __shared__ int lcur[256];       // per-node local cursors (<=197 used)
  int b = blockIdx.x;
  int t = threadIdx.x;
  int lo = bucket_lo(b, N);
  int lo1 = bucket_lo(b + 1, N);
  int rs = cursor[lo];
  int re = (b == NBUCK - 1) ? E : cursor[lo1];
  int count = re - rs;
  int nlocal = lo1 - lo;
  if (count <= PB_CAP) {
    if (t < nlocal) lcur[t] = cursor[lo + t] - rs;
    __syncthreads();
    for (int i = t; i < count; i += 256) {
      u32x4 r = binned[rs + i];  // coalesced
      int d = (int)r[3];
      int p = atomicAdd(&lcur[d - lo], 1);
      lrec[p] = r;
    }
    __syncthreads();
    for (int i = t; i < count; i += 256) csr[rs + i] = lrec[i];  // coalesced
  } else {
    // overflow fallback (statistically never): global scatter
    for (int i = t; i < count; i += 256) {
      u32x4 r = binned[rs + i];
      int p = atomicAdd(&cursor2[(int)r[3]], 1);
      csr[p] = r;
    }
  }
}

// agg1: thread per node; 7-channel gather-accumulate; p1 = x + agg (f32 x8).
__global__ __launch_bounds__(256) void agg1_kernel(
    const float* __restrict__ x, const u32x4* __restrict__ csr,
    const float* __restrict__ We1, const float* __restrict__ be1,
    const int* __restrict__ deg, const int* __restrict__ cursor,
    float* __restrict__ p1, int N) {
  int n = blockIdx.x * 256 + threadIdx.x;
  if (n >= N) return;
  float w[28], b[7];
#pragma unroll
  for (int i = 0; i < 28; ++i) w[i] = We1[i];
#pragma unroll
  for (int i = 0; i < 7; ++i) b[i] = be1[i];
  int start = cursor[n];
  int end = start + deg[n];
  float acc[7];
#pragma unroll
  for (int c = 0; c < 7; ++c) acc[c] = 0.f;
  for (int i = start; i < end; ++i) {
    u32x4 u = __builtin_nontemporal_load(&csr[i]);
    int s = (int)u[0];
    float a0 = __uint_as_float(u[1] << 16);
    float a1 = __uint_as_float(u[1] & 0xffff0000u);
    float a2 = __uint_as_float(u[2] << 16);
    float a3 = __uint_as_float(u[2] & 0xffff0000u);
    const float* xs = x + (size_t)s * 7;
#pragma unroll
    for (int c = 0; c < 7; ++c) {
      float v = b[c] + a0 * w[c] + a1 * w[7 + c] + a2 * w[14 + c] +
                a3 * w[21 + c] + xs[c];
      acc[c] += fmaxf(v, 0.f);
    }
  }
  const float* xn = x + (size_t)n * 7;
#pragma unroll
  for (int c = 0; c < 7; ++c) p1[(size_t)n * 8 + c] = acc[c] + xn[c];
  p1[(size_t)n * 8 + 7] = 0.f;
}

// agg2: wave per node, quarter-parallel; writes p2 bf16[N][64].
__global__ __launch_bounds__(256) void agg2_kernel(
    const unsigned short* __restrict__ h1b, const u32x4* __restrict__ csr,
    const int* __restrict__ deg, const int* __restrict__ cursor,
    const float* __restrict__ We2, const float* __restrict__ be2,
    unsigned short* __restrict__ p2b, int N) {
  int w = threadIdx.x >> 6, j = threadIdx.x & 63;
  int q = j >> 4;  // edge slot 0..3
  int m = j & 15;  // channel quad
  float4 ew0 = *reinterpret_cast<const float4*>(&We2[0 * 64 + m * 4]);
  float4 ew1 = *reinterpret_cast<const float4*>(&We2[1 * 64 + m * 4]);
  float4 ew2 = *reinterpret_cast<const float4*>(&We2[2 * 64 + m * 4]);
  float4 ew3 = *reinterpret_cast<const float4*>(&We2[3 * 64 + m * 4]);
  float4 eb = *reinterpret_cast<const float4*>(&be2[m * 4]);
  int wid = blockIdx.x * 4 + w;
  int nw = gridDim.x * 4;
  for (int n = wid; n < N; n += nw) {
    int start = cursor[n];
    int end = start + deg[n];
    float acc0 = 0.f, acc1 = 0.f, acc2 = 0.f, acc3 = 0.f;
    for (int base = start; base < end; base += 64) {
      int cnt = min(64, end - base);
      int sl = 0;
      int ax = 0, ay = 0;
      if (base + j < end) {
        u32x4 u = __builtin_nontemporal_load(&csr[base + j]);
        sl = (int)u[0];
        ax = (int)u[1];
        ay = (int)u[2];
      }
      int ngrp = (cnt + 3) >> 2;
      for (int it = 0; it < ngrp; ++it) {
        int lane = it * 4 + q;
        int s = __shfl(sl, lane);
        unsigned uax = (unsigned)__shfl(ax, lane);
        unsigned uay = (unsigned)__shfl(ay, lane);
        ushort4 hv =
            *reinterpret_cast<const ushort4*>(&h1b[(size_t)s * 64 + m * 4]);
        float a0 = __uint_as_float(uax << 16);
        float a1 = __uint_as_float(uax & 0xffff0000u);
        float a2 = __uint_as_float(uay << 16);
        float a3 = __uint_as_float(uay & 0xffff0000u);
        float e0 = eb.x + a0 * ew0.x + a1 * ew1.x + a2 * ew2.x + a3 * ew3.x;
        float e1 = eb.y + a0 * ew0.y + a1 * ew1.y + a2 * ew2.y + a3 * ew3.y;
        float e2 = eb.z + a0 * ew0.z + a1 * ew1.z + a2 * ew2.z + a3 * ew3.z;
        float e3 = eb.w + a0 * ew0.w + a1 * ew1.w + a2 * ew2.w + a3 * ew3.w;
        if (lane < cnt) {
          acc0 += fmaxf(bf2f(hv.x) + e0, 0.f);
          acc1 += fmaxf(bf2f(hv.y) + e1, 0.f);
          acc2 += fmaxf(bf2f(hv.z) + e2, 0.f);
          acc3 += fmaxf(bf2f(hv.w) + e3, 0.f);
        }
      }
    }
    acc0 += __shfl_xor(acc0, 16); acc0 += __shfl_xor(acc0, 32);
    acc1 += __shfl_xor(acc1, 16); acc1 += __shfl_xor(acc1, 32);
    acc2 += __shfl_xor(acc2, 16); acc2 += __shfl_xor(acc2, 32);
    acc3 += __shfl_xor(acc3, 16); acc3 += __shfl_xor(acc3, 32);
    ushort4 sv =
        *reinterpret_cast<const ushort4*>(&h1b[(size_t)n * 64 + m * 4]);
    if (q == 0) {
      ushort4 o;
      o.x = f2bf(acc0 + bf2f(sv.x));
      o.y = f2bf(acc1 + bf2f(sv.y));
      o.z = f2bf(acc2 + bf2f(sv.z));
      o.w = f2bf(acc3 + bf2f(sv.w));
      *reinterpret_cast<ushort4*>(&p2b[(size_t)n * 64 + m * 4]) = o;
    }
  }
}

// Fused 2-layer MLP via MFMA 16x16x32 bf16 (m89-verified layouts).
template <int KIN>
__global__ __launch_bounds__(256) void mlp_mfma_kernel(
    const void* __restrict__ pin, const float* __restrict__ Wa,
    const float* __restrict__ ba, const float* __restrict__ Wb,
    const float* __restrict__ bb, unsigned short* __restrict__ hout, int N) {
  __shared__ unsigned short t_lds[4][16 * 72];
  int w = threadIdx.x >> 6, l = threadIdx.x & 63;
  int lr = l & 15, lq = l >> 4;
  constexpr int KSA = (KIN == 8) ? 1 : 2;
  constexpr int VROWS = (KIN == 8) ? 7 : 64;
  bf16x8 wa[2][4], wb[2][4];
#pragma unroll
  for (int ks = 0; ks < KSA; ++ks)
#pragma unroll
    for (int c = 0; c < 4; ++c) {
      bf16x8 f;
#pragma unroll
      for (int r = 0; r < 8; ++r) {
        int row = ks * 32 + lq * 8 + r;
        float v = (row < VROWS) ? Wa[row * 64 + c * 16 + lr] : 0.f;
        f[r] = (short)f2bf(v);
      }
      wa[ks][c] = f;
    }
#pragma unroll
  for (int ks = 0; ks < 2; ++ks)
#pragma unroll
    for (int c = 0; c < 4; ++c) {
      bf16x8 f;
#pragma unroll
      for (int r = 0; r < 8; ++r)
        f[r] = (short)f2bf(Wb[(ks * 32 + lq * 8 + r) * 64 + c * 16 + lr]);
      wb[ks][c] = f;
    }
  float vba[4], vbb[4];
#pragma unroll
  for (int c = 0; c < 4; ++c) {
    vba[c] = ba[c * 16 + lr];
    vbb[c] = bb[c * 16 + lr];
  }
  unsigned short* tl = t_lds[w];
  int ntiles = (N + 15) >> 4;
  for (int tile = blockIdx.x * 4 + w; tile < ntiles; tile += gridDim.x * 4) {
    int n0 = tile << 4;
    int arow = n0 + lr;
    bf16x8 af0, af1;
#pragma unroll
    for (int r = 0; r < 8; ++r) { af0[r] = 0; af1[r] = 0; }
    if (KIN == 8) {
      if (lq == 0 && arow < N) {
        const float* pr = (const float*)pin + (size_t)arow * 8;
#pragma unroll
        for (int r = 0; r < 8; ++r) af0[r] = (short)f2bf(pr[r]);
      }
    } else {
      if (arow < N) {
        const unsigned short* pr =
            (const unsigned short*)pin + (size_t)arow * 64 + lq * 8;
        af0 = *(const bf16x8*)(pr);
        af1 = *(const bf16x8*)(pr + 32);
      }
    }
    f32x4 accA[4];
#pragma unroll
    for (int c = 0; c < 4; ++c) {
      f32x4 a = {0.f, 0.f, 0.f, 0.f};
      a = __builtin_amdgcn_mfma_f32_16x16x32_bf16(af0, wa[0][c], a, 0, 0, 0);
      if (KSA == 2)
        a = __builtin_amdgcn_mfma_f32_16x16x32_bf16(af1, wa[1][c], a, 0, 0, 0);
      accA[c] = a;
    }
#pragma unroll
    for (int c = 0; c < 4; ++c)
#pragma unroll
      for (int r = 0; r < 4; ++r) {
        float v = fmaxf(accA[c][r] + vba[c], 0.f);
        tl[(lq * 4 + r) * 72 + c * 16 + lr] = f2bf(v);
      }
    bf16x8 tf0 = *(const bf16x8*)&tl[lr * 72 + lq * 8];
    bf16x8 tf1 = *(const bf16x8*)&tl[lr * 72 + 32 + lq * 8];
#pragma unroll
    for (int c = 0; c < 4; ++c) {
      f32x4 a = {0.f, 0.f, 0.f, 0.f};
      a = __builtin_amdgcn_mfma_f32_16x16x32_bf16(tf0, wb[0][c], a, 0, 0, 0);
      a = __builtin_amdgcn_mfma_f32_16x16x32_bf16(tf1, wb[1][c], a, 0, 0, 0);
#pragma unroll
      for (int r = 0; r < 4; ++r) {
        int row = n0 + lq * 4 + r;
        if (row < N) {
          float v = fmaxf(a[r] + vbb[c], 0.f);
          hout[(size_t)row * 64 + c * 16 + lr] = f2bf(v);
        }
      }
    }
  }
}

__global__ __launch_bounds__(64) void pool_fc_kernel(
    const unsigned short* __restrict__ h2b, const int* __restrict__ batch,
    const float* __restrict__ Wfc, const float* __restrict__ bfc,
    float* __restrict__ out, int N, int G) {
  int g = blockIdx.x;
  int j = threadIdx.x;
  int q = j >> 4;
  int m = j & 15;
  int lo = 0, hi = N;
  while (lo < hi) {
    int mid = (lo + hi) >> 1;
    if (batch[mid] < g) lo = mid + 1; else hi = mid;
  }
  int start = lo;
  lo = start; hi = N;
  while (lo < hi) {
    int mid = (lo + hi) >> 1;
    if (batch[mid] < g + 1) lo = mid + 1; else hi = mid;
  }
  int end = lo;
  int cnt = end - start;
  float s0 = 0.f, s1 = 0.f, s2 = 0.f, s3 = 0.f;
  int ngrp = (cnt + 3) >> 2;
  for (int it = 0; it < ngrp; ++it) {
    int r = start + it * 4 + q;
    if (r < end) {
      ushort4 hv =
          *reinterpret_cast<const ushort4*>(&h2b[(size_t)r * 64 + m * 4]);
      s0 += bf2f(hv.x);
      s1 += bf2f(hv.y);
      s2 += bf2f(hv.z);
      s3 += bf2f(hv.w);
    }
  }
  s0 += __shfl_xor(s0, 16); s0 += __shfl_xor(s0, 32);
  s1 += __shfl_xor(s1, 16); s1 += __shfl_xor(s1, 32);
  s2 += __shfl_xor(s2, 16); s2 += __shfl_xor(s2, 32);
  s3 += __shfl_xor(s3, 16); s3 += __shfl_xor(s3, 32);
  float inv = 1.f / fmaxf((float)cnt, 1.f);
  __shared__ float spool[64];
  if (q == 0) {
    spool[m * 4 + 0] = s0 * inv;
    spool[m * 4 + 1] = s1 * inv;
    spool[m * 4 + 2] = s2 * inv;
    spool[m * 4 + 3] = s3 * inv;
  }
  __syncthreads();
  if (j < 12) {
    float o = bfc[j];
#pragma unroll
    for (int k = 0; k < 64; ++k) o += spool[k] * Wfc[k * 12 + j];
    out[(size_t)g * 12 + j] = o;
  }
}

extern "C" void kernel_launch(void* const* d_in, const int* in_sizes, int n_in,
                              void* d_out, int out_size, void* d_ws,
                              size_t ws_size, hipStream_t stream) {
  const float* x   = (const float*)d_in[0];
  const float* ea  = (const float*)d_in[1];
  const float* We1 = (const float*)d_in[2];
  const float* be1 = (const float*)d_in[3];
  const float* We2 = (const float*)d_in[4];
  const float* be2 = (const float*)d_in[5];
  const float* W1a = (const float*)d_in[6];
  const float* b1a = (const float*)d_in[7];
  const float* W1b = (const float*)d_in[8];
  const float* b1b = (const float*)d_in[9];
  const float* W2a = (const float*)d_in[10];
  const float* b2a = (const float*)d_in[11];
  const float* W2b = (const float*)d_in[12];
  const float* b2b = (const float*)d_in[13];
  const float* Wfc = (const float*)d_in[14];
  const float* bfc = (const float*)d_in[15];
  const int* eidx  = (const int*)d_in[16];
  const int* batch = (const int*)d_in[17];

  int N = in_sizes[0] / 7;
  int E = in_sizes[1] / 4;
  int G = out_size / 12;
  const int* srcIdx = eidx;
  const int* dstIdx = eidx + E;

  char* ws = (char*)d_ws;
  int*   deg      = (int*)ws;             ws += (size_t)N * 4;
  int*   cursor   = (int*)ws;             ws += (size_t)N * 4;
  int*   blockSum = (int*)ws;             ws += 4096;
  int*   blockOff = (int*)ws;             ws += 4096;
  int*   bcur     = (int*)ws;             ws += NBUCK * 4;
  u32x4* csr      = (u32x4*)ws;           ws += (size_t)E * 16;
  float* p1       = (float*)ws;           ws += (size_t)N * 8 * 4;
  unsigned short* h1b = (unsigned short*)ws; ws += (size_t)N * 64 * 2;
  unsigned short* p2b = (unsigned short*)ws; ws += (size_t)N * 64 * 2;
  unsigned short* h2b = (unsigned short*)ws; ws += (size_t)N * 64 * 2;
  int*   cursor2  = (int*)ws;             /* += N*4 */
  // binned overlays p1+h1b (28.8MB >= 25.6MB), both dead until after passB
  u32x4* binned = (u32x4*)p1;

  int nb = (N + CHUNK - 1) / CHUNK;
  int ntiles = (N + 15) / 16;
  int mlpBlocks = (ntiles + 3) / 4;
  if (mlpBlocks > 1024) mlpBlocks = 1024;
  int ntilesA = (E + TILE_A - 1) / TILE_A;
  double invN = 1.0 / (double)N;

  hipMemsetAsync(deg, 0, (size_t)N * 4, stream);
  hist_kernel<<<((E + 3) / 4 + 255) / 256, 256, 0, stream>>>(dstIdx, deg, E);
  scan1_kernel<<<nb, 256, 0, stream>>>(deg, cursor, blockSum, N);
  scan2_kernel<<<1, 256, 0, stream>>>(blockSum, blockOff, nb);
  scan3_kernel<<<(N + 255) / 256, 256, 0, stream>>>(cursor, blockOff, N);
  initb_kernel<<<2, 256, 0, stream>>>(cursor, bcur, N);
  copycur_kernel<<<(N + 255) / 256, 256, 0, stream>>>(cursor, cursor2, N);
  binA_kernel<<<ntilesA, 256, 0, stream>>>(srcIdx, dstIdx, ea, bcur, binned,
                                           E, invN);
  binB_kernel<<<NBUCK, 256, 0, stream>>>(binned, cursor, cursor2, csr, E, N);
  agg1_kernel<<<(N + 255) / 256, 256, 0, stream>>>(x, csr, We1, be1, deg,
                                                   cursor, p1, N);
  mlp_mfma_kernel<8><<<mlpBlocks, 256, 0, stream>>>(p1, W1a, b1a, W1b, b1b,
                                                    h1b, N);
  agg2_kernel<<<2048, 256, 0, stream>>>(h1b, csr, deg, cursor, We2, be2, p2b,
                                        N);
  mlp_mfma_kernel<64><<<mlpBlocks, 256, 0, stream>>>(p2b, W2a, b2a, W2b, b2b,
                                                     h2b, N);
  pool_fc_kernel<<<G, 64, 0, stream>>>(h2b, batch, Wfc, bfc, (float*)d_out, N,
                                       G);
}

// Round 14
// 245.941 us; speedup vs baseline: 2.0674x; 1.1634x over previous
//
#include <hip/hip_runtime.h>
#include <hip/hip_bf16.h>

// ---------------------------------------------------------------------------
// GINE x2 + mean-pool + FC.
// CSR build with NO per-node scattered atomics and NO N-length scans:
//   histB: per-tile LDS histogram of 512 dst-buckets -> bcnt (400K atomics)
//   scanB: 1-block scan of bcnt -> bstart/bcur (exact bucket regions)
//   binA : 2048-edge tiles, LDS counting-sort into buckets, flush runs
//   passB: block=bucket: count records -> deg/cursor (coalesced), LDS sort,
//          coalesced csr write.  Records = {src, ea01, ea23, dst} (bf16 ea).
// agg1 (thread/node) -> p1; mlp_mfma<8> -> h1 bf16;
// agg2 (wave/node quarter-parallel) -> p2 bf16; mlp_mfma<64> -> h2; pool_fc.
// ---------------------------------------------------------------------------

#define NBUCK 512
#define TILE_A 2048
#define PB_CAP 3584  // passB LDS record capacity (mean 3125 + 8 sigma)

typedef __attribute__((ext_vector_type(8))) short bf16x8;
typedef __attribute__((ext_vector_type(4))) float f32x4;
typedef __attribute__((ext_vector_type(4))) unsigned int u32x4;

__device__ __forceinline__ float bf2f(unsigned short u) {
  return __uint_as_float(((unsigned)u) << 16);
}
__device__ __forceinline__ unsigned short f2bf(float f) {
  __hip_bfloat16 hb = __float2bfloat16(f);
  return *reinterpret_cast<unsigned short*>(&hb);
}
__device__ __forceinline__ int bucket_lo(int b, int N) {
  return (int)(((long long)b * N + (NBUCK - 1)) >> 9);  // ceil(b*N/512)
}
// exact floor(d*512/N): float approx + integer fixup
__device__ __forceinline__ int bucket_of(int d, int N, float f512overN) {
  int b = (int)((float)d * f512overN);
  long long d512 = (long long)d << 9;
  if ((long long)(b + 1) * N <= d512) ++b;
  else if ((long long)b * N > d512) --b;
  return b;
}

// per-tile LDS bucket histogram; 512 global atomics per tile.
__global__ __launch_bounds__(256) void histB_kernel(
    const int* __restrict__ dstIdx, int* __restrict__ bcnt, int E, int N,
    float f512overN) {
  __shared__ int cnt[NBUCK];
  int t = threadIdx.x;
  cnt[t] = 0;
  cnt[t + 256] = 0;
  __syncthreads();
  int e0 = blockIdx.x * TILE_A;
  int valid = min(TILE_A, E - e0);
#pragma unroll
  for (int k = 0; k < 8; ++k) {
    int idx = t + k * 256;
    if (idx < valid) {
      int d = dstIdx[e0 + idx];
      atomicAdd(&cnt[bucket_of(d, N, f512overN)], 1);
    }
  }
  __syncthreads();
  if (cnt[t]) atomicAdd(&bcnt[t], cnt[t]);
  if (cnt[t + 256]) atomicAdd(&bcnt[t + 256], cnt[t + 256]);
}

// 1-block exclusive scan of bcnt[512] -> bstart[513], bcur[512].
__global__ __launch_bounds__(256) void scanB_kernel(
    const int* __restrict__ bcnt, int* __restrict__ bstart,
    int* __restrict__ bcur, int E) {
  __shared__ int sd[256];
  int t = threadIdx.x;
  int base = t * 2;
  int v0 = bcnt[base];
  int v1 = bcnt[base + 1];
  int ts = v0 + v1;
  sd[t] = ts;
  __syncthreads();
  for (int off = 1; off < 256; off <<= 1) {
    int xv = (t >= off) ? sd[t - off] : 0;
    __syncthreads();
    sd[t] += xv;
    __syncthreads();
  }
  int excl = sd[t] - ts;
  bstart[base] = excl;
  bstart[base + 1] = excl + v0;
  bcur[base] = excl;
  bcur[base + 1] = excl + v0;
  if (t == 255) bstart[NBUCK] = E;
}

// passA: per-tile LDS counting sort into 512 buckets; flush contiguous runs.
__global__ __launch_bounds__(256) void binA_kernel(
    const int* __restrict__ srcIdx, const int* __restrict__ dstIdx,
    const float* __restrict__ ea, int* __restrict__ bcur,
    u32x4* __restrict__ binned, int E, int N, float f512overN) {
  __shared__ u32x4 recs[TILE_A];  // 32 KB
  __shared__ int cnt[NBUCK];
  __shared__ int off[NBUCK];
  int t = threadIdx.x;
  int e0 = blockIdx.x * TILE_A;
  int valid = min(TILE_A, E - e0);

  cnt[t] = 0;
  cnt[t + 256] = 0;
  __syncthreads();

  u32x4 rec[8];
  int bkt[8], slot[8];
#pragma unroll
  for (int k = 0; k < 8; ++k) {
    int idx = t + k * 256;
    bkt[k] = -1;
    if (idx < valid) {
      int e = e0 + idx;
      int d = dstIdx[e];
      int s = __builtin_nontemporal_load(&srcIdx[e]);
      f32x4 a = __builtin_nontemporal_load(
          reinterpret_cast<const f32x4*>(ea) + e);
      u32x4 v;
      v[0] = (unsigned)s;
      v[1] = (unsigned)f2bf(a[0]) | ((unsigned)f2bf(a[1]) << 16);
      v[2] = (unsigned)f2bf(a[2]) | ((unsigned)f2bf(a[3]) << 16);
      v[3] = (unsigned)d;
      rec[k] = v;
      int b = bucket_of(d, N, f512overN);
      bkt[k] = b;
      slot[k] = atomicAdd(&cnt[b], 1);
    }
  }
  __syncthreads();
  int c0 = cnt[t], c1 = cnt[t + 256];
  for (int o = 1; o < NBUCK; o <<= 1) {
    int v0 = (t >= o) ? cnt[t - o] : 0;
    int v1 = (t + 256 >= o) ? cnt[t + 256 - o] : 0;
    __syncthreads();
    cnt[t] += v0;
    cnt[t + 256] += v1;
    __syncthreads();
  }
  off[t] = cnt[t] - c0;
  off[t + 256] = cnt[t + 256] - c1;
  __syncthreads();
#pragma unroll
  for (int k = 0; k < 8; ++k)
    if (bkt[k] >= 0) recs[off[bkt[k]] + slot[k]] = rec[k];
  __syncthreads();
#pragma unroll
  for (int h = 0; h < 2; ++h) {
    int b = t + h * 256;
    int c = (h == 0) ? c0 : c1;
    if (c > 0) {
      int g = atomicAdd(&bcur[b], c);
      int o = off[b];
      for (int k = 0; k < c; ++k) binned[g + k] = recs[o + k];
    }
  }
}

// passB: block = bucket.  Pass 1 counts per-node deg (records re-read is
// L2-hot), scan -> deg/cursor coalesced write; pass 2 LDS sort + coalesced
// csr write.  Overflow (> PB_CAP): global scatter via self-initialized gcur.
__global__ __launch_bounds__(256) void binB_kernel(
    const u32x4* __restrict__ binned, const int* __restrict__ bstart,
    int* __restrict__ deg, int* __restrict__ cursor, int* __restrict__ gcur,
    u32x4* __restrict__ csr, int N) {
  __shared__ u32x4 lrec[PB_CAP];  // 56 KB
  __shared__ int ldeg[256];
  __shared__ int lcur[256];
  int b = blockIdx.x;
  int t = threadIdx.x;
  int lo = bucket_lo(b, N);
  int lo1 = bucket_lo(b + 1, N);
  int nlocal = lo1 - lo;
  int rs = bstart[b];
  int re = bstart[b + 1];
  int count = re - rs;
  ldeg[t] = 0;
  __syncthreads();
  for (int i = t; i < count; i += 256) {
    int d = (int)binned[rs + i][3];
    atomicAdd(&ldeg[d - lo], 1);
  }
  __syncthreads();
  int c = ldeg[t];
  lcur[t] = c;
  __syncthreads();
  // inclusive scan over 256 in lcur
  for (int o = 1; o < 256; o <<= 1) {
    int v = (t >= o) ? lcur[t - o] : 0;
    __syncthreads();
    lcur[t] += v;
    __syncthreads();
  }
  int excl = lcur[t] - c;
  if (t < nlocal) {
    deg[lo + t] = c;
    cursor[lo + t] = rs + excl;  // coalesced row-start write
  }
  __syncthreads();
  lcur[t] = excl;
  __syncthreads();
  if (count <= PB_CAP) {
    for (int i = t; i < count; i += 256) {
      u32x4 r = binned[rs + i];  // L2-hot second read
      int p = atomicAdd(&lcur[(int)r[3] - lo], 1);
      lrec[p] = r;
    }
    __syncthreads();
    for (int i = t; i < count; i += 256) csr[rs + i] = lrec[i];  // coalesced
  } else {
    if (t < nlocal) gcur[lo + t] = rs + excl;
    __threadfence();
    __syncthreads();
    for (int i = t; i < count; i += 256) {
      u32x4 r = binned[rs + i];
      int p = atomicAdd(&gcur[(int)r[3]], 1);
      csr[p] = r;
    }
  }
}

// agg1: thread per node; 7-channel gather-accumulate; p1 = x + agg (f32 x8).
__global__ __launch_bounds__(256) void agg1_kernel(
    const float* __restrict__ x, const u32x4* __restrict__ csr,
    const float* __restrict__ We1, const float* __restrict__ be1,
    const int* __restrict__ deg, const int* __restrict__ cursor,
    float* __restrict__ p1, int N) {
  int n = blockIdx.x * 256 + threadIdx.x;
  if (n >= N) return;
  float w[28], b[7];
#pragma unroll
  for (int i = 0; i < 28; ++i) w[i] = We1[i];
#pragma unroll
  for (int i = 0; i < 7; ++i) b[i] = be1[i];
  int start = cursor[n];
  int end = start + deg[n];
  float acc[7];
#pragma unroll
  for (int c = 0; c < 7; ++c) acc[c] = 0.f;
  for (int i = start; i < end; ++i) {
    u32x4 u = __builtin_nontemporal_load(&csr[i]);
    int s = (int)u[0];
    float a0 = __uint_as_float(u[1] << 16);
    float a1 = __uint_as_float(u[1] & 0xffff0000u);
    float a2 = __uint_as_float(u[2] << 16);
    float a3 = __uint_as_float(u[2] & 0xffff0000u);
    const float* xs = x + (size_t)s * 7;
#pragma unroll
    for (int c = 0; c < 7; ++c) {
      float v = b[c] + a0 * w[c] + a1 * w[7 + c] + a2 * w[14 + c] +
                a3 * w[21 + c] + xs[c];
      acc[c] += fmaxf(v, 0.f);
    }
  }
  const float* xn = x + (size_t)n * 7;
#pragma unroll
  for (int c = 0; c < 7; ++c) p1[(size_t)n * 8 + c] = acc[c] + xn[c];
  p1[(size_t)n * 8 + 7] = 0.f;
}

// agg2: wave per node, quarter-parallel; writes p2 bf16[N][64].
__global__ __launch_bounds__(256) void agg2_kernel(
    const unsigned short* __restrict__ h1b, const u32x4* __restrict__ csr,
    const int* __restrict__ deg, const int* __restrict__ cursor,
    const float* __restrict__ We2, const float* __restrict__ be2,
    unsigned short* __restrict__ p2b, int N) {
  int w = threadIdx.x >> 6, j = threadIdx.x & 63;
  int q = j >> 4;  // edge slot 0..3
  int m = j & 15;  // channel quad
  float4 ew0 = *reinterpret_cast<const float4*>(&We2[0 * 64 + m * 4]);
  float4 ew1 = *reinterpret_cast<const float4*>(&We2[1 * 64 + m * 4]);
  float4 ew2 = *reinterpret_cast<const float4*>(&We2[2 * 64 + m * 4]);
  float4 ew3 = *reinterpret_cast<const float4*>(&We2[3 * 64 + m * 4]);
  float4 eb = *reinterpret_cast<const float4*>(&be2[m * 4]);
  int wid = blockIdx.x * 4 + w;
  int nw = gridDim.x * 4;
  for (int n = wid; n < N; n += nw) {
    int start = cursor[n];
    int end = start + deg[n];
    float acc0 = 0.f, acc1 = 0.f, acc2 = 0.f, acc3 = 0.f;
    for (int base = start; base < end; base += 64) {
      int cnt = min(64, end - base);
      int sl = 0;
      int ax = 0, ay = 0;
      if (base + j < end) {
        u32x4 u = __builtin_nontemporal_load(&csr[base + j]);
        sl = (int)u[0];
        ax = (int)u[1];
        ay = (int)u[2];
      }
      int ngrp = (cnt + 3) >> 2;
      for (int it = 0; it < ngrp; ++it) {
        int lane = it * 4 + q;
        int s = __shfl(sl, lane);
        unsigned uax = (unsigned)__shfl(ax, lane);
        unsigned uay = (unsigned)__shfl(ay, lane);
        ushort4 hv =
            *reinterpret_cast<const ushort4*>(&h1b[(size_t)s * 64 + m * 4]);
        float a0 = __uint_as_float(uax << 16);
        float a1 = __uint_as_float(uax & 0xffff0000u);
        float a2 = __uint_as_float(uay << 16);
        float a3 = __uint_as_float(uay & 0xffff0000u);
        float e0 = eb.x + a0 * ew0.x + a1 * ew1.x + a2 * ew2.x + a3 * ew3.x;
        float e1 = eb.y + a0 * ew0.y + a1 * ew1.y + a2 * ew2.y + a3 * ew3.y;
        float e2 = eb.z + a0 * ew0.z + a1 * ew1.z + a2 * ew2.z + a3 * ew3.z;
        float e3 = eb.w + a0 * ew0.w + a1 * ew1.w + a2 * ew2.w + a3 * ew3.w;
        if (lane < cnt) {
          acc0 += fmaxf(bf2f(hv.x) + e0, 0.f);
          acc1 += fmaxf(bf2f(hv.y) + e1, 0.f);
          acc2 += fmaxf(bf2f(hv.z) + e2, 0.f);
          acc3 += fmaxf(bf2f(hv.w) + e3, 0.f);
        }
      }
    }
    acc0 += __shfl_xor(acc0, 16); acc0 += __shfl_xor(acc0, 32);
    acc1 += __shfl_xor(acc1, 16); acc1 += __shfl_xor(acc1, 32);
    acc2 += __shfl_xor(acc2, 16); acc2 += __shfl_xor(acc2, 32);
    acc3 += __shfl_xor(acc3, 16); acc3 += __shfl_xor(acc3, 32);
    ushort4 sv =
        *reinterpret_cast<const ushort4*>(&h1b[(size_t)n * 64 + m * 4]);
    if (q == 0) {
      ushort4 o;
      o.x = f2bf(acc0 + bf2f(sv.x));
      o.y = f2bf(acc1 + bf2f(sv.y));
      o.z = f2bf(acc2 + bf2f(sv.z));
      o.w = f2bf(acc3 + bf2f(sv.w));
      *reinterpret_cast<ushort4*>(&p2b[(size_t)n * 64 + m * 4]) = o;
    }
  }
}

// Fused 2-layer MLP via MFMA 16x16x32 bf16 (m89-verified layouts).
template <int KIN>
__global__ __launch_bounds__(256) void mlp_mfma_kernel(
    const void* __restrict__ pin, const float* __restrict__ Wa,
    const float* __restrict__ ba, const float* __restrict__ Wb,
    const float* __restrict__ bb, unsigned short* __restrict__ hout, int N) {
  __shared__ unsigned short t_lds[4][16 * 72];
  int w = threadIdx.x >> 6, l = threadIdx.x & 63;
  int lr = l & 15, lq = l >> 4;
  constexpr int KSA = (KIN == 8) ? 1 : 2;
  constexpr int VROWS = (KIN == 8) ? 7 : 64;
  bf16x8 wa[2][4], wb[2][4];
#pragma unroll
  for (int ks = 0; ks < KSA; ++ks)
#pragma unroll
    for (int c = 0; c < 4; ++c) {
      bf16x8 f;
#pragma unroll
      for (int r = 0; r < 8; ++r) {
        int row = ks * 32 + lq * 8 + r;
        float v = (row < VROWS) ? Wa[row * 64 + c * 16 + lr] : 0.f;
        f[r] = (short)f2bf(v);
      }
      wa[ks][c] = f;
    }
#pragma unroll
  for (int ks = 0; ks < 2; ++ks)
#pragma unroll
    for (int c = 0; c < 4; ++c) {
      bf16x8 f;
#pragma unroll
      for (int r = 0; r < 8; ++r)
        f[r] = (short)f2bf(Wb[(ks * 32 + lq * 8 + r) * 64 + c * 16 + lr]);
      wb[ks][c] = f;
    }
  float vba[4], vbb[4];
#pragma unroll
  for (int c = 0; c < 4; ++c) {
    vba[c] = ba[c * 16 + lr];
    vbb[c] = bb[c * 16 + lr];
  }
  unsigned short* tl = t_lds[w];
  int ntiles = (N + 15) >> 4;
  for (int tile = blockIdx.x * 4 + w; tile < ntiles; tile += gridDim.x * 4) {
    int n0 = tile << 4;
    int arow = n0 + lr;
    bf16x8 af0, af1;
#pragma unroll
    for (int r = 0; r < 8; ++r) { af0[r] = 0; af1[r] = 0; }
    if (KIN == 8) {
      if (lq == 0 && arow < N) {
        const float* pr = (const float*)pin + (size_t)arow * 8;
#pragma unroll
        for (int r = 0; r < 8; ++r) af0[r] = (short)f2bf(pr[r]);
      }
    } else {
      if (arow < N) {
        const unsigned short* pr =
            (const unsigned short*)pin + (size_t)arow * 64 + lq * 8;
        af0 = *(const bf16x8*)(pr);
        af1 = *(const bf16x8*)(pr + 32);
      }
    }
    f32x4 accA[4];
#pragma unroll
    for (int c = 0; c < 4; ++c) {
      f32x4 a = {0.f, 0.f, 0.f, 0.f};
      a = __builtin_amdgcn_mfma_f32_16x16x32_bf16(af0, wa[0][c], a, 0, 0, 0);
      if (KSA == 2)
        a = __builtin_amdgcn_mfma_f32_16x16x32_bf16(af1, wa[1][c], a, 0, 0, 0);
      accA[c] = a;
    }
#pragma unroll
    for (int c = 0; c < 4; ++c)
#pragma unroll
      for (int r = 0; r < 4; ++r) {
        float v = fmaxf(accA[c][r] + vba[c], 0.f);
        tl[(lq * 4 + r) * 72 + c * 16 + lr] = f2bf(v);
      }
    bf16x8 tf0 = *(const bf16x8*)&tl[lr * 72 + lq * 8];
    bf16x8 tf1 = *(const bf16x8*)&tl[lr * 72 + 32 + lq * 8];
#pragma unroll
    for (int c = 0; c < 4; ++c) {
      f32x4 a = {0.f, 0.f, 0.f, 0.f};
      a = __builtin_amdgcn_mfma_f32_16x16x32_bf16(tf0, wb[0][c], a, 0, 0, 0);
      a = __builtin_amdgcn_mfma_f32_16x16x32_bf16(tf1, wb[1][c], a, 0, 0, 0);
#pragma unroll
      for (int r = 0; r < 4; ++r) {
        int row = n0 + lq * 4 + r;
        if (row < N) {
          float v = fmaxf(a[r] + vbb[c], 0.f);
          hout[(size_t)row * 64 + c * 16 + lr] = f2bf(v);
        }
      }
    }
  }
}

__global__ __launch_bounds__(64) void pool_fc_kernel(
    const unsigned short* __restrict__ h2b, const int* __restrict__ batch,
    const float* __restrict__ Wfc, const float* __restrict__ bfc,
    float* __restrict__ out, int N, int G) {
  int g = blockIdx.x;
  int j = threadIdx.x;
  int q = j >> 4;
  int m = j & 15;
  int lo = 0, hi = N;
  while (lo < hi) {
    int mid = (lo + hi) >> 1;
    if (batch[mid] < g) lo = mid + 1; else hi = mid;
  }
  int start = lo;
  lo = start; hi = N;
  while (lo < hi) {
    int mid = (lo + hi) >> 1;
    if (batch[mid] < g + 1) lo = mid + 1; else hi = mid;
  }
  int end = lo;
  int cnt = end - start;
  float s0 = 0.f, s1 = 0.f, s2 = 0.f, s3 = 0.f;
  int ngrp = (cnt + 3) >> 2;
  for (int it = 0; it < ngrp; ++it) {
    int r = start + it * 4 + q;
    if (r < end) {
      ushort4 hv =
          *reinterpret_cast<const ushort4*>(&h2b[(size_t)r * 64 + m * 4]);
      s0 += bf2f(hv.x);
      s1 += bf2f(hv.y);
      s2 += bf2f(hv.z);
      s3 += bf2f(hv.w);
    }
  }
  s0 += __shfl_xor(s0, 16); s0 += __shfl_xor(s0, 32);
  s1 += __shfl_xor(s1, 16); s1 += __shfl_xor(s1, 32);
  s2 += __shfl_xor(s2, 16); s2 += __shfl_xor(s2, 32);
  s3 += __shfl_xor(s3, 16); s3 += __shfl_xor(s3, 32);
  float inv = 1.f / fmaxf((float)cnt, 1.f);
  __shared__ float spool[64];
  if (q == 0) {
    spool[m * 4 + 0] = s0 * inv;
    spool[m * 4 + 1] = s1 * inv;
    spool[m * 4 + 2] = s2 * inv;
    spool[m * 4 + 3] = s3 * inv;
  }
  __syncthreads();
  if (j < 12) {
    float o = bfc[j];
#pragma unroll
    for (int k = 0; k < 64; ++k) o += spool[k] * Wfc[k * 12 + j];
    out[(size_t)g * 12 + j] = o;
  }
}

extern "C" void kernel_launch(void* const* d_in, const int* in_sizes, int n_in,
                              void* d_out, int out_size, void* d_ws,
                              size_t ws_size, hipStream_t stream) {
  const float* x   = (const float*)d_in[0];
  const float* ea  = (const float*)d_in[1];
  const float* We1 = (const float*)d_in[2];
  const float* be1 = (const float*)d_in[3];
  const float* We2 = (const float*)d_in[4];
  const float* be2 = (const float*)d_in[5];
  const float* W1a = (const float*)d_in[6];
  const float* b1a = (const float*)d_in[7];
  const float* W1b = (const float*)d_in[8];
  const float* b1b = (const float*)d_in[9];
  const float* W2a = (const float*)d_in[10];
  const float* b2a = (const float*)d_in[11];
  const float* W2b = (const float*)d_in[12];
  const float* b2b = (const float*)d_in[13];
  const float* Wfc = (const float*)d_in[14];
  const float* bfc = (const float*)d_in[15];
  const int* eidx  = (const int*)d_in[16];
  const int* batch = (const int*)d_in[17];

  int N = in_sizes[0] / 7;
  int E = in_sizes[1] / 4;
  int G = out_size / 12;
  const int* srcIdx = eidx;
  const int* dstIdx = eidx + E;

  char* ws = (char*)d_ws;
  int*   deg      = (int*)ws;             ws += (size_t)N * 4;
  int*   cursor   = (int*)ws;             ws += (size_t)N * 4;
  int*   gcur     = (int*)ws;             ws += (size_t)N * 4;
  int*   bcnt     = (int*)ws;             ws += NBUCK * 4;
  int*   bstart   = (int*)ws;             ws += (NBUCK + 1) * 4;
  int*   bcur     = (int*)ws;             ws += NBUCK * 4;
  ws = (char*)(((size_t)ws + 255) & ~(size_t)255);
  u32x4* csr      = (u32x4*)ws;           ws += (size_t)E * 16;
  float* p1       = (float*)ws;           ws += (size_t)N * 8 * 4;
  unsigned short* h1b = (unsigned short*)ws; ws += (size_t)N * 64 * 2;
  unsigned short* p2b = (unsigned short*)ws; ws += (size_t)N * 64 * 2;
  unsigned short* h2b = (unsigned short*)ws; /* += N*64*2 */
  // binned overlays p1+h1b (28.8MB >= 25.6MB), both dead until after passB
  u32x4* binned = (u32x4*)p1;

  int ntiles = (N + 15) / 16;
  int mlpBlocks = (ntiles + 3) / 4;
  if (mlpBlocks > 1024) mlpBlocks = 1024;
  int ntilesA = (E + TILE_A - 1) / TILE_A;
  float f512overN = 512.0f / (float)N;

  hipMemsetAsync(bcnt, 0, NBUCK * 4, stream);
  histB_kernel<<<ntilesA, 256, 0, stream>>>(dstIdx, bcnt, E, N, f512overN);
  scanB_kernel<<<1, 256, 0, stream>>>(bcnt, bstart, bcur, E);
  binA_kernel<<<ntilesA, 256, 0, stream>>>(srcIdx, dstIdx, ea, bcur, binned,
                                           E, N, f512overN);
  binB_kernel<<<NBUCK, 256, 0, stream>>>(binned, bstart, deg, cursor, gcur,
                                         csr, N);
  agg1_kernel<<<(N + 255) / 256, 256, 0, stream>>>(x, csr, We1, be1, deg,
                                                   cursor, p1, N);
  mlp_mfma_kernel<8><<<mlpBlocks, 256, 0, stream>>>(p1, W1a, b1a, W1b, b1b,
                                                    h1b, N);
  agg2_kernel<<<2048, 256, 0, stream>>>(h1b, csr, deg, cursor, We2, be2, p2b,
                                        N);
  mlp_mfma_kernel<64><<<mlpBlocks, 256, 0, stream>>>(p2b, W2a, b2a, W2b, b2b,
                                                     h2b, N);
  pool_fc_kernel<<<G, 64, 0, stream>>>(h2b, batch, Wfc, bfc, (float*)d_out, N,
                                       G);
}

// Round 15
// 206.649 us; speedup vs baseline: 2.4605x; 1.1901x over previous
//
#include <hip/hip_runtime.h>
#include <hip/hip_bf16.h>

// ---------------------------------------------------------------------------
// GINE x2 + mean-pool + FC.
// CSR build with NO per-node scattered atomics and NO N-length scans:
//   histB: per-tile LDS histogram of 512 dst-buckets -> bcnt
//   scanB: 1-block scan -> bstart/bcur
//   binA : 2048-edge tiles, LDS counting-sort into buckets, flush runs
//   binB : block=bucket: count -> deg/cursor (coalesced), LDS sort,
//          coalesced csr write, THEN FUSED conv1-aggregate (records already
//          in LDS; x[src] gathers are L2-resident) -> p1 f32[N][8].
// mlp_mfma<8> -> h1 bf16; agg2 (wave/node quarter-parallel) -> p2 bf16;
// mlp_mfma<64> -> h2; pool_fc.
// binned overlays p2b+h2b (dead until after binB).
// ---------------------------------------------------------------------------

#define NBUCK 512
#define TILE_A 2048
#define PB_CAP 3584  // passB LDS record capacity (mean 3125 + 8 sigma)

typedef __attribute__((ext_vector_type(8))) short bf16x8;
typedef __attribute__((ext_vector_type(4))) float f32x4;
typedef __attribute__((ext_vector_type(4))) unsigned int u32x4;

__device__ __forceinline__ float bf2f(unsigned short u) {
  return __uint_as_float(((unsigned)u) << 16);
}
__device__ __forceinline__ unsigned short f2bf(float f) {
  __hip_bfloat16 hb = __float2bfloat16(f);
  return *reinterpret_cast<unsigned short*>(&hb);
}
__device__ __forceinline__ int bucket_lo(int b, int N) {
  return (int)(((long long)b * N + (NBUCK - 1)) >> 9);  // ceil(b*N/512)
}
// exact floor(d*512/N): float approx + integer fixup
__device__ __forceinline__ int bucket_of(int d, int N, float f512overN) {
  int b = (int)((float)d * f512overN);
  long long d512 = (long long)d << 9;
  if ((long long)(b + 1) * N <= d512) ++b;
  else if ((long long)b * N > d512) --b;
  return b;
}

__global__ __launch_bounds__(256) void histB_kernel(
    const int* __restrict__ dstIdx, int* __restrict__ bcnt, int E, int N,
    float f512overN) {
  __shared__ int cnt[NBUCK];
  int t = threadIdx.x;
  cnt[t] = 0;
  cnt[t + 256] = 0;
  __syncthreads();
  int e0 = blockIdx.x * TILE_A;
  int valid = min(TILE_A, E - e0);
#pragma unroll
  for (int k = 0; k < 8; ++k) {
    int idx = t + k * 256;
    if (idx < valid) {
      int d = dstIdx[e0 + idx];
      atomicAdd(&cnt[bucket_of(d, N, f512overN)], 1);
    }
  }
  __syncthreads();
  if (cnt[t]) atomicAdd(&bcnt[t], cnt[t]);
  if (cnt[t + 256]) atomicAdd(&bcnt[t + 256], cnt[t + 256]);
}

__global__ __launch_bounds__(256) void scanB_kernel(
    const int* __restrict__ bcnt, int* __restrict__ bstart,
    int* __restrict__ bcur, int E) {
  __shared__ int sd[256];
  int t = threadIdx.x;
  int base = t * 2;
  int v0 = bcnt[base];
  int v1 = bcnt[base + 1];
  int ts = v0 + v1;
  sd[t] = ts;
  __syncthreads();
  for (int off = 1; off < 256; off <<= 1) {
    int xv = (t >= off) ? sd[t - off] : 0;
    __syncthreads();
    sd[t] += xv;
    __syncthreads();
  }
  int excl = sd[t] - ts;
  bstart[base] = excl;
  bstart[base + 1] = excl + v0;
  bcur[base] = excl;
  bcur[base + 1] = excl + v0;
  if (t == 255) bstart[NBUCK] = E;
}

// passA: per-tile LDS counting sort into 512 buckets; flush contiguous runs.
__global__ __launch_bounds__(256) void binA_kernel(
    const int* __restrict__ srcIdx, const int* __restrict__ dstIdx,
    const float* __restrict__ ea, int* __restrict__ bcur,
    u32x4* __restrict__ binned, int E, int N, float f512overN) {
  __shared__ u32x4 recs[TILE_A];  // 32 KB
  __shared__ int cnt[NBUCK];
  __shared__ int off[NBUCK];
  int t = threadIdx.x;
  int e0 = blockIdx.x * TILE_A;
  int valid = min(TILE_A, E - e0);

  cnt[t] = 0;
  cnt[t + 256] = 0;
  __syncthreads();

  u32x4 rec[8];
  int bkt[8], slot[8];
#pragma unroll
  for (int k = 0; k < 8; ++k) {
    int idx = t + k * 256;
    bkt[k] = -1;
    if (idx < valid) {
      int e = e0 + idx;
      int d = dstIdx[e];
      int s = __builtin_nontemporal_load(&srcIdx[e]);
      f32x4 a = __builtin_nontemporal_load(
          reinterpret_cast<const f32x4*>(ea) + e);
      u32x4 v;
      v[0] = (unsigned)s;
      v[1] = (unsigned)f2bf(a[0]) | ((unsigned)f2bf(a[1]) << 16);
      v[2] = (unsigned)f2bf(a[2]) | ((unsigned)f2bf(a[3]) << 16);
      v[3] = (unsigned)d;
      rec[k] = v;
      int b = bucket_of(d, N, f512overN);
      bkt[k] = b;
      slot[k] = atomicAdd(&cnt[b], 1);
    }
  }
  __syncthreads();
  int c0 = cnt[t], c1 = cnt[t + 256];
  for (int o = 1; o < NBUCK; o <<= 1) {
    int v0 = (t >= o) ? cnt[t - o] : 0;
    int v1 = (t + 256 >= o) ? cnt[t + 256 - o] : 0;
    __syncthreads();
    cnt[t] += v0;
    cnt[t + 256] += v1;
    __syncthreads();
  }
  off[t] = cnt[t] - c0;
  off[t + 256] = cnt[t + 256] - c1;
  __syncthreads();
#pragma unroll
  for (int k = 0; k < 8; ++k)
    if (bkt[k] >= 0) recs[off[bkt[k]] + slot[k]] = rec[k];
  __syncthreads();
#pragma unroll
  for (int h = 0; h < 2; ++h) {
    int b = t + h * 256;
    int c = (h == 0) ? c0 : c1;
    if (c > 0) {
      int g = atomicAdd(&bcur[b], c);
      int o = off[b];
      for (int k = 0; k < c; ++k) binned[g + k] = recs[o + k];
    }
  }
}

// passB: block = bucket.  Count -> deg/cursor; LDS sort; coalesced csr write;
// FUSED conv1-aggregate from LDS records -> p1 (x gathers are L2-resident).
__global__ __launch_bounds__(256) void binB_kernel(
    const u32x4* __restrict__ binned, const int* __restrict__ bstart,
    int* __restrict__ deg, int* __restrict__ cursor, int* __restrict__ gcur,
    u32x4* __restrict__ csr, const float* __restrict__ x,
    const float* __restrict__ We1, const float* __restrict__ be1,
    float* __restrict__ p1, int N) {
  __shared__ u32x4 lrec[PB_CAP];  // 56 KB
  __shared__ int ldeg[256];
  __shared__ int lcur[256];
  int b = blockIdx.x;
  int t = threadIdx.x;
  int lo = bucket_lo(b, N);
  int lo1 = bucket_lo(b + 1, N);
  int nlocal = lo1 - lo;  // <= 196 < 256 by construction
  int rs = bstart[b];
  int re = bstart[b + 1];
  int count = re - rs;
  float w1[28], b1[7];
#pragma unroll
  for (int i = 0; i < 28; ++i) w1[i] = We1[i];  // uniform -> SGPR
#pragma unroll
  for (int i = 0; i < 7; ++i) b1[i] = be1[i];
  ldeg[t] = 0;
  __syncthreads();
  for (int i = t; i < count; i += 256) {
    int d = (int)binned[rs + i][3];
    atomicAdd(&ldeg[d - lo], 1);
  }
  __syncthreads();
  int c = ldeg[t];
  lcur[t] = c;
  __syncthreads();
  for (int o = 1; o < 256; o <<= 1) {
    int v = (t >= o) ? lcur[t - o] : 0;
    __syncthreads();
    lcur[t] += v;
    __syncthreads();
  }
  int excl = lcur[t] - c;
  if (t < nlocal) {
    deg[lo + t] = c;
    cursor[lo + t] = rs + excl;  // coalesced row-start write
  }
  __syncthreads();
  lcur[t] = excl;
  __syncthreads();
  bool fits = (count <= PB_CAP);
  if (fits) {
    for (int i = t; i < count; i += 256) {
      u32x4 r = binned[rs + i];  // L2-hot second read
      int p = atomicAdd(&lcur[(int)r[3] - lo], 1);
      lrec[p] = r;
    }
    __syncthreads();
    for (int i = t; i < count; i += 256) csr[rs + i] = lrec[i];  // coalesced
  } else {
    // overflow fallback (statistically never): global scatter
    if (t < nlocal) gcur[lo + t] = rs + excl;
    __threadfence();
    __syncthreads();
    for (int i = t; i < count; i += 256) {
      u32x4 r = binned[rs + i];
      int p = atomicAdd(&gcur[(int)r[3]], 1);
      csr[p] = r;
    }
    __threadfence();
    __syncthreads();
  }
  // ---- fused conv1 aggregate: node lo+t owns records [excl, excl+c) ----
  if (t < nlocal) {
    float acc[7];
#pragma unroll
    for (int ch = 0; ch < 7; ++ch) acc[ch] = 0.f;
    for (int i = excl; i < excl + c; ++i) {
      u32x4 r = fits ? lrec[i] : csr[rs + i];
      int s = (int)r[0];
      float a0 = __uint_as_float(r[1] << 16);
      float a1 = __uint_as_float(r[1] & 0xffff0000u);
      float a2 = __uint_as_float(r[2] << 16);
      float a3 = __uint_as_float(r[2] & 0xffff0000u);
      const float* xs = x + (size_t)s * 7;  // random 28B, L2-resident
#pragma unroll
      for (int ch = 0; ch < 7; ++ch) {
        float v = b1[ch] + a0 * w1[ch] + a1 * w1[7 + ch] + a2 * w1[14 + ch] +
                  a3 * w1[21 + ch] + xs[ch];
        acc[ch] += fmaxf(v, 0.f);
      }
    }
    const float* xn = x + (size_t)(lo + t) * 7;
#pragma unroll
    for (int ch = 0; ch < 7; ++ch)
      p1[(size_t)(lo + t) * 8 + ch] = acc[ch] + xn[ch];
    p1[(size_t)(lo + t) * 8 + 7] = 0.f;
  }
}

// agg2: wave per node, quarter-parallel; writes p2 bf16[N][64].
__global__ __launch_bounds__(256) void agg2_kernel(
    const unsigned short* __restrict__ h1b, const u32x4* __restrict__ csr,
    const int* __restrict__ deg, const int* __restrict__ cursor,
    const float* __restrict__ We2, const float* __restrict__ be2,
    unsigned short* __restrict__ p2b, int N) {
  int w = threadIdx.x >> 6, j = threadIdx.x & 63;
  int q = j >> 4;  // edge slot 0..3
  int m = j & 15;  // channel quad
  float4 ew0 = *reinterpret_cast<const float4*>(&We2[0 * 64 + m * 4]);
  float4 ew1 = *reinterpret_cast<const float4*>(&We2[1 * 64 + m * 4]);
  float4 ew2 = *reinterpret_cast<const float4*>(&We2[2 * 64 + m * 4]);
  float4 ew3 = *reinterpret_cast<const float4*>(&We2[3 * 64 + m * 4]);
  float4 eb = *reinterpret_cast<const float4*>(&be2[m * 4]);
  int wid = blockIdx.x * 4 + w;
  int nw = gridDim.x * 4;
  for (int n = wid; n < N; n += nw) {
    int start = cursor[n];
    int end = start + deg[n];
    float acc0 = 0.f, acc1 = 0.f, acc2 = 0.f, acc3 = 0.f;
    for (int base = start; base < end; base += 64) {
      int cnt = min(64, end - base);
      int sl = 0;
      int ax = 0, ay = 0;
      if (base + j < end) {
        u32x4 u = csr[base + j];  // coalesced 16B, cached (L3 test)
        sl = (int)u[0];
        ax = (int)u[1];
        ay = (int)u[2];
      }
      int ngrp = (cnt + 3) >> 2;
      for (int it = 0; it < ngrp; ++it) {
        int lane = it * 4 + q;
        int s = __shfl(sl, lane);
        unsigned uax = (unsigned)__shfl(ax, lane);
        unsigned uay = (unsigned)__shfl(ay, lane);
        ushort4 hv =
            *reinterpret_cast<const ushort4*>(&h1b[(size_t)s * 64 + m * 4]);
        float a0 = __uint_as_float(uax << 16);
        float a1 = __uint_as_float(uax & 0xffff0000u);
        float a2 = __uint_as_float(uay << 16);
        float a3 = __uint_as_float(uay & 0xffff0000u);
        float e0 = eb.x + a0 * ew0.x + a1 * ew1.x + a2 * ew2.x + a3 * ew3.x;
        float e1 = eb.y + a0 * ew0.y + a1 * ew1.y + a2 * ew2.y + a3 * ew3.y;
        float e2 = eb.z + a0 * ew0.z + a1 * ew1.z + a2 * ew2.z + a3 * ew3.z;
        float e3 = eb.w + a0 * ew0.w + a1 * ew1.w + a2 * ew2.w + a3 * ew3.w;
        if (lane < cnt) {
          acc0 += fmaxf(bf2f(hv.x) + e0, 0.f);
          acc1 += fmaxf(bf2f(hv.y) + e1, 0.f);
          acc2 += fmaxf(bf2f(hv.z) + e2, 0.f);
          acc3 += fmaxf(bf2f(hv.w) + e3, 0.f);
        }
      }
    }
    acc0 += __shfl_xor(acc0, 16); acc0 += __shfl_xor(acc0, 32);
    acc1 += __shfl_xor(acc1, 16); acc1 += __shfl_xor(acc1, 32);
    acc2 += __shfl_xor(acc2, 16); acc2 += __shfl_xor(acc2, 32);
    acc3 += __shfl_xor(acc3, 16); acc3 += __shfl_xor(acc3, 32);
    ushort4 sv =
        *reinterpret_cast<const ushort4*>(&h1b[(size_t)n * 64 + m * 4]);
    if (q == 0) {
      ushort4 o;
      o.x = f2bf(acc0 + bf2f(sv.x));
      o.y = f2bf(acc1 + bf2f(sv.y));
      o.z = f2bf(acc2 + bf2f(sv.z));
      o.w = f2bf(acc3 + bf2f(sv.w));
      *reinterpret_cast<ushort4*>(&p2b[(size_t)n * 64 + m * 4]) = o;
    }
  }
}

// Fused 2-layer MLP via MFMA 16x16x32 bf16 (m89-verified layouts).
template <int KIN>
__global__ __launch_bounds__(256) void mlp_mfma_kernel(
    const void* __restrict__ pin, const float* __restrict__ Wa,
    const float* __restrict__ ba, const float* __restrict__ Wb,
    const float* __restrict__ bb, unsigned short* __restrict__ hout, int N) {
  __shared__ unsigned short t_lds[4][16 * 72];
  int w = threadIdx.x >> 6, l = threadIdx.x & 63;
  int lr = l & 15, lq = l >> 4;
  constexpr int KSA = (KIN == 8) ? 1 : 2;
  constexpr int VROWS = (KIN == 8) ? 7 : 64;
  bf16x8 wa[2][4], wb[2][4];
#pragma unroll
  for (int ks = 0; ks < KSA; ++ks)
#pragma unroll
    for (int c = 0; c < 4; ++c) {
      bf16x8 f;
#pragma unroll
      for (int r = 0; r < 8; ++r) {
        int row = ks * 32 + lq * 8 + r;
        float v = (row < VROWS) ? Wa[row * 64 + c * 16 + lr] : 0.f;
        f[r] = (short)f2bf(v);
      }
      wa[ks][c] = f;
    }
#pragma unroll
  for (int ks = 0; ks < 2; ++ks)
#pragma unroll
    for (int c = 0; c < 4; ++c) {
      bf16x8 f;
#pragma unroll
      for (int r = 0; r < 8; ++r)
        f[r] = (short)f2bf(Wb[(ks * 32 + lq * 8 + r) * 64 + c * 16 + lr]);
      wb[ks][c] = f;
    }
  float vba[4], vbb[4];
#pragma unroll
  for (int c = 0; c < 4; ++c) {
    vba[c] = ba[c * 16 + lr];
    vbb[c] = bb[c * 16 + lr];
  }
  unsigned short* tl = t_lds[w];
  int ntiles = (N + 15) >> 4;
  for (int tile = blockIdx.x * 4 + w; tile < ntiles; tile += gridDim.x * 4) {
    int n0 = tile << 4;
    int arow = n0 + lr;
    bf16x8 af0, af1;
#pragma unroll
    for (int r = 0; r < 8; ++r) { af0[r] = 0; af1[r] = 0; }
    if (KIN == 8) {
      if (lq == 0 && arow < N) {
        const float* pr = (const float*)pin + (size_t)arow * 8;
#pragma unroll
        for (int r = 0; r < 8; ++r) af0[r] = (short)f2bf(pr[r]);
      }
    } else {
      if (arow < N) {
        const unsigned short* pr =
            (const unsigned short*)pin + (size_t)arow * 64 + lq * 8;
        af0 = *(const bf16x8*)(pr);
        af1 = *(const bf16x8*)(pr + 32);
      }
    }
    f32x4 accA[4];
#pragma unroll
    for (int c = 0; c < 4; ++c) {
      f32x4 a = {0.f, 0.f, 0.f, 0.f};
      a = __builtin_amdgcn_mfma_f32_16x16x32_bf16(af0, wa[0][c], a, 0, 0, 0);
      if (KSA == 2)
        a = __builtin_amdgcn_mfma_f32_16x16x32_bf16(af1, wa[1][c], a, 0, 0, 0);
      accA[c] = a;
    }
#pragma unroll
    for (int c = 0; c < 4; ++c)
#pragma unroll
      for (int r = 0; r < 4; ++r) {
        float v = fmaxf(accA[c][r] + vba[c], 0.f);
        tl[(lq * 4 + r) * 72 + c * 16 + lr] = f2bf(v);
      }
    bf16x8 tf0 = *(const bf16x8*)&tl[lr * 72 + lq * 8];
    bf16x8 tf1 = *(const bf16x8*)&tl[lr * 72 + 32 + lq * 8];
#pragma unroll
    for (int c = 0; c < 4; ++c) {
      f32x4 a = {0.f, 0.f, 0.f, 0.f};
      a = __builtin_amdgcn_mfma_f32_16x16x32_bf16(tf0, wb[0][c], a, 0, 0, 0);
      a = __builtin_amdgcn_mfma_f32_16x16x32_bf16(tf1, wb[1][c], a, 0, 0, 0);
#pragma unroll
      for (int r = 0; r < 4; ++r) {
        int row = n0 + lq * 4 + r;
        if (row < N) {
          float v = fmaxf(a[r] + vbb[c], 0.f);
          hout[(size_t)row * 64 + c * 16 + lr] = f2bf(v);
        }
      }
    }
  }
}

__global__ __launch_bounds__(64) void pool_fc_kernel(
    const unsigned short* __restrict__ h2b, const int* __restrict__ batch,
    const float* __restrict__ Wfc, const float* __restrict__ bfc,
    float* __restrict__ out, int N, int G) {
  int g = blockIdx.x;
  int j = threadIdx.x;
  int q = j >> 4;
  int m = j & 15;
  int lo = 0, hi = N;
  while (lo < hi) {
    int mid = (lo + hi) >> 1;
    if (batch[mid] < g) lo = mid + 1; else hi = mid;
  }
  int start = lo;
  lo = start; hi = N;
  while (lo < hi) {
    int mid = (lo + hi) >> 1;
    if (batch[mid] < g + 1) lo = mid + 1; else hi = mid;
  }
  int end = lo;
  int cnt = end - start;
  float s0 = 0.f, s1 = 0.f, s2 = 0.f, s3 = 0.f;
  int ngrp = (cnt + 3) >> 2;
  for (int it = 0; it < ngrp; ++it) {
    int r = start + it * 4 + q;
    if (r < end) {
      ushort4 hv =
          *reinterpret_cast<const ushort4*>(&h2b[(size_t)r * 64 + m * 4]);
      s0 += bf2f(hv.x);
      s1 += bf2f(hv.y);
      s2 += bf2f(hv.z);
      s3 += bf2f(hv.w);
    }
  }
  s0 += __shfl_xor(s0, 16); s0 += __shfl_xor(s0, 32);
  s1 += __shfl_xor(s1, 16); s1 += __shfl_xor(s1, 32);
  s2 += __shfl_xor(s2, 16); s2 += __shfl_xor(s2, 32);
  s3 += __shfl_xor(s3, 16); s3 += __shfl_xor(s3, 32);
  float inv = 1.f / fmaxf((float)cnt, 1.f);
  __shared__ float spool[64];
  if (q == 0) {
    spool[m * 4 + 0] = s0 * inv;
    spool[m * 4 + 1] = s1 * inv;
    spool[m * 4 + 2] = s2 * inv;
    spool[m * 4 + 3] = s3 * inv;
  }
  __syncthreads();
  if (j < 12) {
    float o = bfc[j];
#pragma unroll
    for (int k = 0; k < 64; ++k) o += spool[k] * Wfc[k * 12 + j];
    out[(size_t)g * 12 + j] = o;
  }
}

extern "C" void kernel_launch(void* const* d_in, const int* in_sizes, int n_in,
                              void* d_out, int out_size, void* d_ws,
                              size_t ws_size, hipStream_t stream) {
  const float* x   = (const float*)d_in[0];
  const float* ea  = (const float*)d_in[1];
  const float* We1 = (const float*)d_in[2];
  const float* be1 = (const float*)d_in[3];
  const float* We2 = (const float*)d_in[4];
  const float* be2 = (const float*)d_in[5];
  const float* W1a = (const float*)d_in[6];
  const float* b1a = (const float*)d_in[7];
  const float* W1b = (const float*)d_in[8];
  const float* b1b = (const float*)d_in[9];
  const float* W2a = (const float*)d_in[10];
  const float* b2a = (const float*)d_in[11];
  const float* W2b = (const float*)d_in[12];
  const float* b2b = (const float*)d_in[13];
  const float* Wfc = (const float*)d_in[14];
  const float* bfc = (const float*)d_in[15];
  const int* eidx  = (const int*)d_in[16];
  const int* batch = (const int*)d_in[17];

  int N = in_sizes[0] / 7;
  int E = in_sizes[1] / 4;
  int G = out_size / 12;
  const int* srcIdx = eidx;
  const int* dstIdx = eidx + E;

  char* ws = (char*)d_ws;
  int*   deg      = (int*)ws;             ws += (size_t)N * 4;
  int*   cursor   = (int*)ws;             ws += (size_t)N * 4;
  int*   gcur     = (int*)ws;             ws += (size_t)N * 4;
  int*   bcnt     = (int*)ws;             ws += NBUCK * 4;
  int*   bstart   = (int*)ws;             ws += (NBUCK + 1) * 4;
  int*   bcur     = (int*)ws;             ws += NBUCK * 4;
  ws = (char*)(((size_t)ws + 255) & ~(size_t)255);
  u32x4* csr      = (u32x4*)ws;           ws += (size_t)E * 16;
  float* p1       = (float*)ws;           ws += (size_t)N * 8 * 4;
  unsigned short* h1b = (unsigned short*)ws; ws += (size_t)N * 64 * 2;
  unsigned short* p2b = (unsigned short*)ws; ws += (size_t)N * 64 * 2;
  unsigned short* h2b = (unsigned short*)ws; /* += N*64*2 */
  // binned overlays p2b+h2b (12.8+12.8 = 25.6 MB = E*16), dead until binB done
  u32x4* binned = (u32x4*)p2b;

  int ntiles = (N + 15) / 16;
  int mlpBlocks = (ntiles + 3) / 4;
  if (mlpBlocks > 1024) mlpBlocks = 1024;
  int ntilesA = (E + TILE_A - 1) / TILE_A;
  float f512overN = 512.0f / (float)N;

  hipMemsetAsync(bcnt, 0, NBUCK * 4, stream);
  histB_kernel<<<ntilesA, 256, 0, stream>>>(dstIdx, bcnt, E, N, f512overN);
  scanB_kernel<<<1, 256, 0, stream>>>(bcnt, bstart, bcur, E);
  binA_kernel<<<ntilesA, 256, 0, stream>>>(srcIdx, dstIdx, ea, bcur, binned,
                                           E, N, f512overN);
  binB_kernel<<<NBUCK, 256, 0, stream>>>(binned, bstart, deg, cursor, gcur,
                                         csr, x, We1, be1, p1, N);
  mlp_mfma_kernel<8><<<mlpBlocks, 256, 0, stream>>>(p1, W1a, b1a, W1b, b1b,
                                                    h1b, N);
  agg2_kernel<<<2048, 256, 0, stream>>>(h1b, csr, deg, cursor, We2, be2, p2b,
                                        N);
  mlp_mfma_kernel<64><<<mlpBlocks, 256, 0, stream>>>(p2b, W2a, b2a, W2b, b2b,
                                                     h2b, N);
  pool_fc_kernel<<<G, 64, 0, stream>>>(h2b, batch, Wfc, bfc, (float*)d_out, N,
                                       G);
}